// Round 6
// baseline (749.857 us; speedup 1.0000x reference)
//
#include <hip/hip_runtime.h>
#include <hip/hip_bf16.h>
#include <type_traits>

// out = sum_b A_b @ (X @ W_b) + bias
// 1) hist      : LDS-aggregated bucket histogram (bucket = row>>6)
// 2) scan      : excl scan of padded region sizes (round8(cnt)+SG_PAD)
// 3) bscatter  : LDS-binned scatter, every global write a full 64B chunk
//                (drain pads partial rings with {0,0} sentinels = exact no-ops)
// 4) gemm      : Y[n,512] = X @ W' (fp32 compute, bf16 store, hop-major cols)
// 5) sortgather: block per bucket: LDS counting-sort (u16 rank index) +
//                wave-per-16-rows register gather, coalesced Y reads, + bias

#define NBUK_MAX 800
#define RCAP 7168      // payloads per bucket held in LDS (mean ~4990 incl pad)
#define SG_PAD 2048    // per-bucket region pad >= 7 * BSCAT_BLOCKS, mult of 8
#define BSCAT_BLOCKS 256

// ---------------- GEMM ----------------
template <typename YT>
__global__ __launch_bounds__(256, 2) void gemm_kernel(
    const float* __restrict__ X, const float* __restrict__ W,
    YT* __restrict__ Y, int n_rows, int col0, int ystride)
{
  __shared__ float Xs[64][128];
  __shared__ float Ws[128][64];
  const int tid = threadIdx.x;
  const int row0 = blockIdx.y * 64;

  {
    const int lane = tid & 31;
    const int r = tid >> 5;
#pragma unroll
    for (int i = 0; i < 8; ++i) {
      const int rr = r + i * 8;
      const int gr = row0 + rr;
      float4 v = make_float4(0.f, 0.f, 0.f, 0.f);
      if (gr < n_rows) v = ((const float4*)(X + (size_t)gr * 128))[lane];
      ((float4*)&Xs[rr][0])[lane ^ ((rr >> 2) & 7)] = v;
    }
  }
  {
    const int gc0 = col0 + blockIdx.x * 64;
    const int b = gc0 >> 7;
    const int cc0 = gc0 & 127;
    const float* Wb = W + (size_t)b * 128 * 128 + cc0;
    const int lane16 = tid & 15;
    const int f = tid >> 4;
#pragma unroll
    for (int i = 0; i < 8; ++i) {
      const int ff = f + i * 16;
      const float4 v = *(const float4*)(Wb + (size_t)ff * 128 + lane16 * 4);
      ((float4*)&Ws[ff][0])[lane16] = v;
    }
  }
  __syncthreads();

  const int tx = tid & 15;
  const int ty = tid >> 4;
  float acc[4][4] = {};
#pragma unroll 2
  for (int f0 = 0; f0 < 128; f0 += 4) {
    float4 a[4];
#pragma unroll
    for (int i = 0; i < 4; ++i) {
      const int r = ty * 4 + i;
      a[i] = ((const float4*)&Xs[r][0])[(f0 >> 2) ^ ((r >> 2) & 7)];
    }
#pragma unroll
    for (int k = 0; k < 4; ++k) {
      const float4 b = *(const float4*)&Ws[f0 + k][tx * 4];
#pragma unroll
      for (int i = 0; i < 4; ++i) {
        const float av = (&a[i].x)[k];
        acc[i][0] = fmaf(av, b.x, acc[i][0]);
        acc[i][1] = fmaf(av, b.y, acc[i][1]);
        acc[i][2] = fmaf(av, b.z, acc[i][2]);
        acc[i][3] = fmaf(av, b.w, acc[i][3]);
      }
    }
  }
  const int yc = blockIdx.x * 64 + tx * 4;
#pragma unroll
  for (int i = 0; i < 4; ++i) {
    const int gr = row0 + ty * 4 + i;
    if (gr >= n_rows) continue;
    if constexpr (std::is_same<YT, float>::value) {
      *(float4*)(Y + (size_t)gr * ystride + yc) =
          make_float4(acc[i][0], acc[i][1], acc[i][2], acc[i][3]);
    } else {
      union { ushort4 u; __hip_bfloat16 h[4]; } p;
      p.h[0] = __float2bfloat16(acc[i][0]);
      p.h[1] = __float2bfloat16(acc[i][1]);
      p.h[2] = __float2bfloat16(acc[i][2]);
      p.h[3] = __float2bfloat16(acc[i][3]);
      *(ushort4*)(Y + (size_t)gr * ystride + yc) = p.u;
    }
  }
}

// ---------------- bucket histogram ----------------
__global__ __launch_bounds__(256) void hist_kernel(
    const int* __restrict__ rows, int* __restrict__ cnt, unsigned ntot, int nbuk)
{
  __shared__ int lcnt[NBUK_MAX];
  for (int i = threadIdx.x; i < nbuk; i += 256) lcnt[i] = 0;
  __syncthreads();
  for (unsigned e = blockIdx.x * 256u + threadIdx.x; e < ntot; e += gridDim.x * 256u)
    atomicAdd(&lcnt[((unsigned)rows[e]) >> 6], 1);
  __syncthreads();
  for (int i = threadIdx.x; i < nbuk; i += 256)
    if (lcnt[i]) atomicAdd(&cnt[i], lcnt[i]);
}

// ---------------- scan of padded region sizes ----------------
__global__ __launch_bounds__(1024) void scan_kernel(
    const int* __restrict__ cnt, int* __restrict__ pstart,
    int* __restrict__ gcur, int nbuk)
{
  __shared__ int buf[1024];
  const int t = threadIdx.x;
  const int v = (t < nbuk) ? (((cnt[t] + 7) & ~7) + SG_PAD) : 0;
  buf[t] = v;
  __syncthreads();
  for (int off = 1; off < 1024; off <<= 1) {
    const int add = (t >= off) ? buf[t - off] : 0;
    __syncthreads();
    buf[t] += add;
    __syncthreads();
  }
  if (t < nbuk) { pstart[t] = buf[t] - v; gcur[t] = buf[t] - v; }
}

// ---------------- LDS-binned scatter, full-chunk writes ----------------
// payload: x = row<<16 | col ; y = hop<<30 | val_bits (val in [0,1) => 30 bits)
// sentinel {0,0}: rl=0, col=0, hop=0, val=+0.0 -> exact no-op for consumer.
__global__ __launch_bounds__(256) void bscatter_kernel(
    const int* __restrict__ rows, const int* __restrict__ cols,
    const float* __restrict__ vals, int* __restrict__ gcur,
    uint2* __restrict__ staged, unsigned ntot, unsigned epb, int nbuk)
{
  __shared__ int bcnt[NBUK_MAX];
  __shared__ uint2 bins[NBUK_MAX * 8];
  for (int i = threadIdx.x; i < nbuk; i += 256) bcnt[i] = 0;
  __syncthreads();

  const unsigned chunk = (ntot + gridDim.x - 1) / gridDim.x;
  const unsigned beg = blockIdx.x * chunk;
  const unsigned end = (beg + chunk < ntot) ? (beg + chunk) : ntot;

  for (unsigned base = beg; base < end; base += 1024) {
#pragma unroll
    for (int k = 0; k < 4; ++k) {
      const unsigned e = base + (unsigned)k * 256u + threadIdx.x;
      if (e < end) {
        const unsigned r = (unsigned)rows[e];
        const unsigned c = (unsigned)cols[e];
        const unsigned hop = (e >= 2u * epb) ? ((e >= 3u * epb) ? 3u : 2u)
                                             : ((e >= epb) ? 1u : 0u);
        const uint2 pay = make_uint2((r << 16) | c,
                                     (hop << 30) | __float_as_uint(vals[e]));
        const int bk = (int)(r >> 6);
        const int p = atomicAdd(&bcnt[bk], 1);
        if (p < 8) bins[bk * 8 + p] = pay;
        else {  // rare intra-tile overflow: direct single write
          const int gp = atomicAdd(&gcur[bk], 1);
          staged[gp] = pay;
        }
      }
    }
    __syncthreads();
    for (int bk = threadIdx.x; bk < nbuk; bk += 256) {
      if (bcnt[bk] >= 8) {
        const int gp = atomicAdd(&gcur[bk], 8);
        uint2* dst = staged + gp;
#pragma unroll
        for (int q = 0; q < 8; ++q) dst[q] = bins[bk * 8 + q];
        bcnt[bk] = 0;
      }
    }
    __syncthreads();
  }
  // drain: pad partial rings to full 64B chunks with sentinels
  for (int bk = threadIdx.x; bk < nbuk; bk += 256) {
    const int c = bcnt[bk];
    if (c > 0) {
      const int gp = atomicAdd(&gcur[bk], 8);
      uint2* dst = staged + gp;
#pragma unroll
      for (int q = 0; q < 8; ++q)
        dst[q] = (q < c) ? bins[bk * 8 + q] : make_uint2(0u, 0u);
    }
  }
}

// ---------------- fused counting-sort + gather ----------------
__global__ __launch_bounds__(256) void sortgather_kernel(
    const int* __restrict__ pstart, const int* __restrict__ gcur,
    const uint2* __restrict__ staged, const __hip_bfloat16* __restrict__ Y,
    const float* __restrict__ bias, float* __restrict__ out, int n)
{
  __shared__ uint2 lbuf[RCAP];
  __shared__ unsigned short sidx[RCAP];
  __shared__ int lcnt[64], lstart[64], lcur[64];
  const int bk = blockIdx.x;
  const int s = pstart[bk];
  const int fc = gcur[bk] - s;      // filled count incl. sentinels
  const int tid = threadIdx.x;
  const int w = tid >> 6;
  const int lane = tid & 63;
  const float2 bb = *(const float2*)(bias + lane * 2);

  auto yload = [&](uint2 p) -> float2 {
    const unsigned yoff = (p.x & 0xFFFFu) * 512u + (p.y >> 30) * 128u;
    const __hip_bfloat162 h = *(const __hip_bfloat162*)(Y + (size_t)yoff + lane * 2);
    const float v = __uint_as_float(p.y & 0x3FFFFFFFu);
    return make_float2(v * __low2float(h), v * __high2float(h));
  };

  if (fc > RCAP) {  // pathological skew: slow but correct direct path
    for (int r = w * 16; r < w * 16 + 16; ++r) {
      const int gr = bk * 64 + r;
      if (gr >= n) break;
      float ax = 0.f, ay = 0.f;
      for (int j = 0; j < fc; ++j) {
        const uint2 p = staged[s + j];
        if ((int)((p.x >> 16) & 63u) == r) {
          const float2 t = yload(p);
          ax += t.x; ay += t.y;
        }
      }
      *(float2*)(out + (size_t)gr * 128 + lane * 2) =
          make_float2(ax + bb.x, ay + bb.y);
    }
    return;
  }

  if (tid < 64) lcnt[tid] = 0;
  __syncthreads();
  for (int j = tid; j < fc; j += 256) {
    const uint2 p = staged[s + j];
    lbuf[j] = p;
    atomicAdd(&lcnt[(p.x >> 16) & 63u], 1);
  }
  __syncthreads();
  if (tid == 0) {
    int a = 0;
    for (int i = 0; i < 64; ++i) { lstart[i] = a; lcur[i] = a; a += lcnt[i]; }
  }
  __syncthreads();
  for (int j = tid; j < fc; j += 256) {
    const unsigned rl = (lbuf[j].x >> 16) & 63u;
    sidx[atomicAdd(&lcur[rl], 1)] = (unsigned short)j;
  }
  __syncthreads();

  for (int r = w * 16; r < w * 16 + 16; ++r) {
    const int gr = bk * 64 + r;
    if (gr >= n) break;
    const int js = lstart[r];
    const int je = js + lcnt[r];
    float ax = 0.f, ay = 0.f;
    int j = js;
    for (; j + 3 < je; j += 4) {
      const uint2 p0 = lbuf[sidx[j]];
      const uint2 p1 = lbuf[sidx[j + 1]];
      const uint2 p2 = lbuf[sidx[j + 2]];
      const uint2 p3 = lbuf[sidx[j + 3]];
      const float2 t0 = yload(p0), t1 = yload(p1), t2 = yload(p2), t3 = yload(p3);
      ax += (t0.x + t1.x) + (t2.x + t3.x);
      ay += (t0.y + t1.y) + (t2.y + t3.y);
    }
    for (; j < je; ++j) {
      const float2 t = yload(lbuf[sidx[j]]);
      ax += t.x; ay += t.y;
    }
    *(float2*)(out + (size_t)gr * 128 + lane * 2) =
        make_float2(ax + bb.x, ay + bb.y);
  }
}

// ---------------- fallback (atomic path) ----------------
__global__ __launch_bounds__(256) void init_out_kernel(
    float* __restrict__ out, const float* __restrict__ bias, int nquads)
{
  int i = blockIdx.x * blockDim.x + threadIdx.x;
  if (i >= nquads) return;
  const float4 b = ((const float4*)bias)[i & 31];
  ((float4*)out)[i] = b;
}

__global__ __launch_bounds__(256) void scatter_kernel(
    const int* __restrict__ rows, const int* __restrict__ cols,
    const float* __restrict__ vals, const float* __restrict__ Y,
    int ystride, int yblk, unsigned epb, unsigned ntot,
    float* __restrict__ out)
{
  const unsigned e = blockIdx.x * 8u + (threadIdx.x >> 5);
  if (e >= ntot) return;
  const int lane = threadIdx.x & 31;
  const int row = rows[e];
  const int col = cols[e];
  const float v = vals[e];
  const unsigned b = e / epb;
  const float4 y = *(const float4*)(Y + (size_t)col * ystride + (size_t)b * yblk + lane * 4);
  float* o = out + (size_t)row * 128 + lane * 4;
  atomicAdd(o + 0, v * y.x);
  atomicAdd(o + 1, v * y.y);
  atomicAdd(o + 2, v * y.z);
  atomicAdd(o + 3, v * y.w);
}

extern "C" void kernel_launch(void* const* d_in, const int* in_sizes, int n_in,
                              void* d_out, int out_size, void* d_ws, size_t ws_size,
                              hipStream_t stream) {
  const float* X    = (const float*)d_in[0];
  const int*   rows = (const int*)d_in[1];
  const int*   cols = (const int*)d_in[2];
  const float* vals = (const float*)d_in[3];
  const float* W    = (const float*)d_in[4];
  const float* bias = (const float*)d_in[5];
  float* out = (float*)d_out;

  const int n = out_size / 128;                 // 50000
  const unsigned ntot = (unsigned)in_sizes[1];  // 3.2M flat
  const unsigned epb = ntot / 4u;
  const int nbuk = (n + 63) >> 6;               // 782

  auto align = [](size_t x) { return (x + 255) & ~(size_t)255; };
  const size_t sz_cnt    = align((size_t)nbuk * 4);
  const size_t sz_pstart = align((size_t)nbuk * 4);
  const size_t sz_gcur   = align((size_t)nbuk * 4);
  const size_t sz_staged = align(((size_t)ntot + (size_t)nbuk * (8 + SG_PAD)) * 8);
  const size_t sz_y_bf16 = align((size_t)n * 512 * 2);
  const size_t meta = sz_cnt + sz_pstart + sz_gcur + sz_staged;

  char* ws = (char*)d_ws;
  int*   cnt    = (int*)(ws);
  int*   pstart = (int*)(ws + sz_cnt);
  int*   gcur   = (int*)(ws + sz_cnt + sz_pstart);
  uint2* staged = (uint2*)(ws + sz_cnt + sz_pstart + sz_gcur);
  __hip_bfloat16* Y = (__hip_bfloat16*)(ws + meta);

  const bool fast_ok = (n <= 65536) && (nbuk <= NBUK_MAX) && (nbuk <= 1024) &&
                       (ntot % 4u == 0u) && (in_sizes[0] == n * 128) &&
                       (ws_size >= meta + sz_y_bf16);

  if (fast_ok) {
    hipMemsetAsync(cnt, 0, (size_t)nbuk * 4, stream);
    hist_kernel<<<dim3(256), dim3(256), 0, stream>>>(rows, cnt, ntot, nbuk);
    scan_kernel<<<dim3(1), dim3(1024), 0, stream>>>(cnt, pstart, gcur, nbuk);
    bscatter_kernel<<<dim3(BSCAT_BLOCKS), dim3(256), 0, stream>>>(
        rows, cols, vals, gcur, staged, ntot, epb, nbuk);
    dim3 g(512 / 64, (n + 63) / 64);
    gemm_kernel<__hip_bfloat16><<<g, dim3(256), 0, stream>>>(X, W, Y, n, 0, 512);
    sortgather_kernel<<<dim3(nbuk), dim3(256), 0, stream>>>(
        pstart, gcur, staged, Y, bias, out, n);
    return;
  }

  // Fallback: atomic path
  {
    const int nquads = n * 32;
    init_out_kernel<<<dim3((nquads + 255) / 256), dim3(256), 0, stream>>>(out, bias, nquads);
    float* Yf = (float*)d_ws;
    const size_t need_fused = (size_t)n * 512 * sizeof(float);
    if (ws_size >= need_fused) {
      dim3 g(512 / 64, (n + 63) / 64);
      gemm_kernel<float><<<g, dim3(256), 0, stream>>>(X, W, Yf, n, 0, 512);
      const unsigned nblk = (ntot + 7) / 8;
      scatter_kernel<<<dim3(nblk), dim3(256), 0, stream>>>(
          rows, cols, vals, Yf, 512, 128, epb, ntot, out);
    } else {
      for (unsigned b = 0; b < 4; ++b) {
        dim3 g(128 / 64, (n + 63) / 64);
        gemm_kernel<float><<<g, dim3(256), 0, stream>>>(X, W, Yf, n, (int)(b * 128), 128);
        const unsigned nblk = (epb + 7) / 8;
        scatter_kernel<<<dim3(nblk), dim3(256), 0, stream>>>(
            rows + (size_t)b * epb, cols + (size_t)b * epb, vals + (size_t)b * epb,
            Yf, 128, 0, epb, epb, out);
      }
    }
  }
}

// Round 7
// 376.087 us; speedup vs baseline: 1.9938x; 1.9938x over previous
//
#include <hip/hip_runtime.h>
#include <hip/hip_bf16.h>
#include <type_traits>

// out = sum_b A_b @ (X @ W_b) + bias
// 1) hist    : LDS-aggregated bucket histogram (bucket = row>>6), int4 loads
// 2) scan2   : excl scans (8-padded -> staged regions, exact -> ep regions)
// 3) bscatter: LDS-binned scatter, single-writer 64B flushes -> staged
// 4) prep    : X -> bf16 [n][128]; W -> Wt bf16 [512 gc][128 f] (K-contig)
// 5) mfma    : Y[n,512] = Xb @ Wt^T via v_mfma_f32_16x16x32_bf16, LDS-free
// 6) reorder : per-bucket LDS counting sort -> exact row-CSR ep + row_start
// 7) gather  : one wave per row, register accumulate, coalesced Y reads

#define NBUK_MAX 800
#define RCAP 6144
#define BSCAT_BLOCKS 256

typedef __attribute__((ext_vector_type(8))) short short8;
typedef __attribute__((ext_vector_type(4))) float f32x4;

static __device__ __forceinline__ ushort f2bf(float f) {
  __hip_bfloat16 h = __float2bfloat16(f);
  return *(ushort*)&h;
}

// ---------------- prep: X->bf16, W->transposed bf16 ----------------
__global__ __launch_bounds__(256) void prep_kernel(
    const float* __restrict__ X, const float* __restrict__ W,
    ushort* __restrict__ Xb, ushort* __restrict__ Wt, int nx8)
{
  const int t = blockIdx.x * 256 + threadIdx.x;
  if (t < nx8) {
    const float4 v0 = ((const float4*)X)[t * 2];
    const float4 v1 = ((const float4*)X)[t * 2 + 1];
    ushort4 o0, o1;
    o0.x = f2bf(v0.x); o0.y = f2bf(v0.y); o0.z = f2bf(v0.z); o0.w = f2bf(v0.w);
    o1.x = f2bf(v1.x); o1.y = f2bf(v1.y); o1.z = f2bf(v1.z); o1.w = f2bf(v1.w);
    ((ushort4*)Xb)[t * 2] = o0;
    ((ushort4*)Xb)[t * 2 + 1] = o1;
  } else if (t < nx8 + 8192) {
    const int u = t - nx8;            // 512 gc * 16 chunks
    const int gc = u >> 4;
    const int f0 = (u & 15) * 8;
    const float* src = W + (size_t)((gc >> 7) * 128) * 128 + (gc & 127);
    ushort4 o0, o1;
    o0.x = f2bf(src[(size_t)(f0 + 0) * 128]);
    o0.y = f2bf(src[(size_t)(f0 + 1) * 128]);
    o0.z = f2bf(src[(size_t)(f0 + 2) * 128]);
    o0.w = f2bf(src[(size_t)(f0 + 3) * 128]);
    o1.x = f2bf(src[(size_t)(f0 + 4) * 128]);
    o1.y = f2bf(src[(size_t)(f0 + 5) * 128]);
    o1.z = f2bf(src[(size_t)(f0 + 6) * 128]);
    o1.w = f2bf(src[(size_t)(f0 + 7) * 128]);
    ((ushort4*)(Wt + (size_t)gc * 128 + f0))[0] = o0;
    ((ushort4*)(Wt + (size_t)gc * 128 + f0))[1] = o1;
  }
}

// ---------------- MFMA GEMM: Y[row][gc] = sum_f Xb[row][f] * Wt[gc][f] ----
// grid (8, ceil(n/64)), 4 waves; wave w: rows [by*64+w*16, +16), cols [bx*64, +64)
__global__ __launch_bounds__(256) void mfma_gemm_kernel(
    const ushort* __restrict__ Xb, const ushort* __restrict__ Wt,
    ushort* __restrict__ Y, int n)
{
  const int w = threadIdx.x >> 6;
  const int l = threadIdx.x & 63;
  const int r16 = l & 15;
  const int kg = l >> 4;              // 0..3
  const int row0 = blockIdx.y * 64 + w * 16;
  const int c0 = blockIdx.x * 64;

  const int gra = min(row0 + r16, n - 1);
  const ushort* ap = Xb + (size_t)gra * 128 + kg * 8;
  const ushort* bp = Wt + (size_t)(c0 + r16) * 128 + kg * 8;

  f32x4 acc[4] = {};
#pragma unroll
  for (int k0 = 0; k0 < 128; k0 += 32) {
    const short8 a = *(const short8*)(ap + k0);
#pragma unroll
    for (int ct = 0; ct < 4; ++ct) {
      const short8 b = *(const short8*)(bp + (size_t)ct * 16 * 128 + k0);
      acc[ct] = __builtin_amdgcn_mfma_f32_16x16x32_bf16(a, b, acc[ct], 0, 0, 0);
    }
  }
  // C/D: row = (l>>4)*4 + r, col = l&15   [m89-verified]
  const int rs0 = row0 + kg * 4;
#pragma unroll
  for (int ct = 0; ct < 4; ++ct) {
    const int col = c0 + ct * 16 + r16;
#pragma unroll
    for (int r = 0; r < 4; ++r) {
      const int rs = rs0 + r;
      if (rs < n) Y[(size_t)rs * 512 + col] = f2bf(acc[ct][r]);
    }
  }
}

// ---------------- bucket histogram (int4 loads) ----------------
__global__ __launch_bounds__(256) void hist_kernel(
    const int* __restrict__ rows, int* __restrict__ cnt, unsigned ntot, int nbuk)
{
  __shared__ int lcnt[NBUK_MAX];
  for (int i = threadIdx.x; i < nbuk; i += 256) lcnt[i] = 0;
  __syncthreads();
  const unsigned nq = ntot >> 2;
  for (unsigned i = blockIdx.x * 256u + threadIdx.x; i < nq; i += gridDim.x * 256u) {
    const int4 r4 = ((const int4*)rows)[i];
    atomicAdd(&lcnt[((unsigned)r4.x) >> 6], 1);
    atomicAdd(&lcnt[((unsigned)r4.y) >> 6], 1);
    atomicAdd(&lcnt[((unsigned)r4.z) >> 6], 1);
    atomicAdd(&lcnt[((unsigned)r4.w) >> 6], 1);
  }
  __syncthreads();
  for (int i = threadIdx.x; i < nbuk; i += 256)
    if (lcnt[i]) atomicAdd(&cnt[i], lcnt[i]);
}

// ---------------- dual scans ----------------
__global__ __launch_bounds__(1024) void scan2_kernel(
    const int* __restrict__ cnt, int* __restrict__ pstart8,
    int* __restrict__ pstartX, int* __restrict__ gcur,
    int* __restrict__ row_start, int nbuk, int n, unsigned ntot)
{
  __shared__ int buf[1024];
  const int t = threadIdx.x;
  const int c = (t < nbuk) ? cnt[t] : 0;
  int v = (c + 7) & ~7;
  buf[t] = v;
  __syncthreads();
  for (int off = 1; off < 1024; off <<= 1) {
    const int add = (t >= off) ? buf[t - off] : 0;
    __syncthreads();
    buf[t] += add;
    __syncthreads();
  }
  if (t < nbuk) { pstart8[t] = buf[t] - v; gcur[t] = buf[t] - v; }
  __syncthreads();
  buf[t] = c;
  __syncthreads();
  for (int off = 1; off < 1024; off <<= 1) {
    const int add = (t >= off) ? buf[t - off] : 0;
    __syncthreads();
    buf[t] += add;
    __syncthreads();
  }
  if (t < nbuk) pstartX[t] = buf[t] - c;
  if (t == 0) row_start[n] = (int)ntot;
}

// ---------------- LDS-binned scatter ----------------
// payload: x = row<<16 | col ; y = hop<<30 | val_bits (val in [0,1) => 30 bits)
__global__ __launch_bounds__(256) void bscatter_kernel(
    const int* __restrict__ rows, const int* __restrict__ cols,
    const float* __restrict__ vals, int* __restrict__ gcur,
    uint2* __restrict__ staged, unsigned ntot, unsigned epb, int nbuk)
{
  __shared__ int bcnt[NBUK_MAX];
  __shared__ uint2 bins[NBUK_MAX * 8];
  for (int i = threadIdx.x; i < nbuk; i += 256) bcnt[i] = 0;
  __syncthreads();

  unsigned chunk = (ntot + gridDim.x - 1) / gridDim.x;
  chunk = (chunk + 3) & ~3u;                    // keep int4 alignment per block
  const unsigned beg = blockIdx.x * chunk;
  const unsigned end = (beg + chunk < ntot) ? (beg + chunk) : ntot;

  auto push = [&](unsigned r, unsigned c, unsigned hop, float v) {
    const uint2 pay = make_uint2((r << 16) | c, (hop << 30) | __float_as_uint(v));
    const int bk = (int)(r >> 6);
    const int p = atomicAdd(&bcnt[bk], 1);
    if (p < 8) bins[bk * 8 + p] = pay;
    else {
      const int gp = atomicAdd(&gcur[bk], 1);
      staged[gp] = pay;
    }
  };

  for (unsigned base = beg; base < end; base += 1024) {
    const unsigned e0 = base + threadIdx.x * 4u;
    if (e0 + 3 < end) {
      const int4 r4 = *(const int4*)(rows + e0);
      const int4 c4 = *(const int4*)(cols + e0);
      const float4 v4 = *(const float4*)(vals + e0);
#pragma unroll
      for (int q = 0; q < 4; ++q) {
        const unsigned e = e0 + q;
        const unsigned hop = (e >= 2u * epb) ? ((e >= 3u * epb) ? 3u : 2u)
                                             : ((e >= epb) ? 1u : 0u);
        const unsigned r = (unsigned)((&r4.x)[q]);
        const unsigned c = (unsigned)((&c4.x)[q]);
        push(r, c, hop, (&v4.x)[q]);
      }
    } else {
      for (unsigned e = e0; e < end && e < e0 + 4; ++e) {
        const unsigned hop = (e >= 2u * epb) ? ((e >= 3u * epb) ? 3u : 2u)
                                             : ((e >= epb) ? 1u : 0u);
        push((unsigned)rows[e], (unsigned)cols[e], hop, vals[e]);
      }
    }
    __syncthreads();
    for (int bk = threadIdx.x; bk < nbuk; bk += 256) {
      if (bcnt[bk] >= 8) {
        const int gp = atomicAdd(&gcur[bk], 8);
        uint2* dst = staged + gp;
#pragma unroll
        for (int q = 0; q < 8; ++q) dst[q] = bins[bk * 8 + q];
        bcnt[bk] = 0;
      }
    }
    __syncthreads();
  }
  for (int bk = threadIdx.x; bk < nbuk; bk += 256) {
    const int c = bcnt[bk];
    if (c > 0) {
      const int gp = atomicAdd(&gcur[bk], c);
      for (int q = 0; q < c; ++q) staged[gp + q] = bins[bk * 8 + q];
    }
  }
}

// ---------------- per-bucket counting sort -> exact CSR ----------------
__global__ __launch_bounds__(256) void reorder_kernel(
    const int* __restrict__ cnt, const int* __restrict__ pstart8,
    const int* __restrict__ pstartX, const uint2* __restrict__ staged,
    uint2* __restrict__ ep, int* __restrict__ row_start, int n)
{
  __shared__ int lcnt[64], lstart[64], lcur[64];
  __shared__ uint2 lbuf[RCAP];
  const int bk = blockIdx.x;
  const int c = cnt[bk];
  const int s8 = pstart8[bk];
  const int sx = pstartX[bk];

  if (threadIdx.x < 64) lcnt[threadIdx.x] = 0;
  __syncthreads();
  for (int j = threadIdx.x; j < c; j += 256)
    atomicAdd(&lcnt[(staged[s8 + j].x >> 16) & 63u], 1);
  __syncthreads();
  if (threadIdx.x == 0) {
    int a = 0;
    for (int i = 0; i < 64; ++i) { lstart[i] = a; lcur[i] = a; a += lcnt[i]; }
  }
  __syncthreads();
  if (threadIdx.x < 64) {
    const int gr = bk * 64 + threadIdx.x;
    if (gr < n) row_start[gr] = sx + lstart[threadIdx.x];
  }
  if (c <= RCAP) {
    for (int j = threadIdx.x; j < c; j += 256) {
      const uint2 p = staged[s8 + j];
      const unsigned rl = (p.x >> 16) & 63u;
      const int pos = atomicAdd(&lcur[rl], 1);
      lbuf[pos] = make_uint2((p.x & 0xFFFFu) * 512u + (p.y >> 30) * 128u,
                             p.y & 0x3FFFFFFFu);
    }
    __syncthreads();
    for (int j = threadIdx.x; j < c; j += 256) ep[sx + j] = lbuf[j];
  } else {
    for (int j = threadIdx.x; j < c; j += 256) {
      const uint2 p = staged[s8 + j];
      const unsigned rl = (p.x >> 16) & 63u;
      const int pos = atomicAdd(&lcur[rl], 1);
      ep[sx + pos] = make_uint2((p.x & 0xFFFFu) * 512u + (p.y >> 30) * 128u,
                                p.y & 0x3FFFFFFFu);
    }
  }
}

// ---------------- gather: one wave per row ----------------
__global__ __launch_bounds__(256) void gather_kernel(
    const int* __restrict__ row_start, const uint2* __restrict__ ep,
    const __hip_bfloat16* __restrict__ Y, const float* __restrict__ bias,
    float* __restrict__ out, int n)
{
  const int wid = (int)((blockIdx.x * 256u + threadIdx.x) >> 6);
  if (wid >= n) return;
  const int lane = threadIdx.x & 63;
  const int js = row_start[wid];
  const int je = row_start[wid + 1];
  float ax = 0.f, ay = 0.f;

  auto ld = [&](uint2 p) -> float2 {
    const __hip_bfloat162 h = *(const __hip_bfloat162*)(Y + (size_t)p.x + lane * 2);
    const float v = __uint_as_float(p.y);
    return make_float2(v * __low2float(h), v * __high2float(h));
  };

  int j = js;
  for (; j + 3 < je; j += 4) {
    const uint2 p0 = ep[j], p1 = ep[j + 1], p2 = ep[j + 2], p3 = ep[j + 3];
    const float2 t0 = ld(p0), t1 = ld(p1), t2 = ld(p2), t3 = ld(p3);
    ax += (t0.x + t1.x) + (t2.x + t3.x);
    ay += (t0.y + t1.y) + (t2.y + t3.y);
  }
  for (; j < je; ++j) {
    const float2 t = ld(ep[j]);
    ax += t.x; ay += t.y;
  }
  const float2 bb = *(const float2*)(bias + lane * 2);
  *(float2*)(out + (size_t)wid * 128 + lane * 2) = make_float2(ax + bb.x, ay + bb.y);
}

// ---------------- fallback (atomic path, fp32 vector gemm) ----------------
template <typename YT>
__global__ __launch_bounds__(256, 2) void gemm_kernel(
    const float* __restrict__ X, const float* __restrict__ W,
    YT* __restrict__ Y, int n_rows, int col0, int ystride)
{
  __shared__ float Xs[64][128];
  __shared__ float Ws[128][64];
  const int tid = threadIdx.x;
  const int row0 = blockIdx.y * 64;
  {
    const int lane = tid & 31;
    const int r = tid >> 5;
#pragma unroll
    for (int i = 0; i < 8; ++i) {
      const int rr = r + i * 8;
      const int gr = row0 + rr;
      float4 v = make_float4(0.f, 0.f, 0.f, 0.f);
      if (gr < n_rows) v = ((const float4*)(X + (size_t)gr * 128))[lane];
      ((float4*)&Xs[rr][0])[lane ^ ((rr >> 2) & 7)] = v;
    }
  }
  {
    const int gc0 = col0 + blockIdx.x * 64;
    const int b = gc0 >> 7;
    const int cc0 = gc0 & 127;
    const float* Wb = W + (size_t)b * 128 * 128 + cc0;
    const int lane16 = tid & 15;
    const int f = tid >> 4;
#pragma unroll
    for (int i = 0; i < 8; ++i) {
      const int ff = f + i * 16;
      const float4 v = *(const float4*)(Wb + (size_t)ff * 128 + lane16 * 4);
      ((float4*)&Ws[ff][0])[lane16] = v;
    }
  }
  __syncthreads();
  const int tx = tid & 15;
  const int ty = tid >> 4;
  float acc[4][4] = {};
#pragma unroll 2
  for (int f0 = 0; f0 < 128; f0 += 4) {
    float4 a[4];
#pragma unroll
    for (int i = 0; i < 4; ++i) {
      const int r = ty * 4 + i;
      a[i] = ((const float4*)&Xs[r][0])[(f0 >> 2) ^ ((r >> 2) & 7)];
    }
#pragma unroll
    for (int k = 0; k < 4; ++k) {
      const float4 b = *(const float4*)&Ws[f0 + k][tx * 4];
#pragma unroll
      for (int i = 0; i < 4; ++i) {
        const float av = (&a[i].x)[k];
        acc[i][0] = fmaf(av, b.x, acc[i][0]);
        acc[i][1] = fmaf(av, b.y, acc[i][1]);
        acc[i][2] = fmaf(av, b.z, acc[i][2]);
        acc[i][3] = fmaf(av, b.w, acc[i][3]);
      }
    }
  }
  const int yc = blockIdx.x * 64 + tx * 4;
#pragma unroll
  for (int i = 0; i < 4; ++i) {
    const int gr = row0 + ty * 4 + i;
    if (gr >= n_rows) continue;
    *(float4*)(Y + (size_t)gr * ystride + yc) =
        make_float4(acc[i][0], acc[i][1], acc[i][2], acc[i][3]);
  }
}

__global__ __launch_bounds__(256) void init_out_kernel(
    float* __restrict__ out, const float* __restrict__ bias, int nquads)
{
  int i = blockIdx.x * blockDim.x + threadIdx.x;
  if (i >= nquads) return;
  const float4 b = ((const float4*)bias)[i & 31];
  ((float4*)out)[i] = b;
}

__global__ __launch_bounds__(256) void scatter_kernel(
    const int* __restrict__ rows, const int* __restrict__ cols,
    const float* __restrict__ vals, const float* __restrict__ Y,
    int ystride, int yblk, unsigned epb, unsigned ntot,
    float* __restrict__ out)
{
  const unsigned e = blockIdx.x * 8u + (threadIdx.x >> 5);
  if (e >= ntot) return;
  const int lane = threadIdx.x & 31;
  const int row = rows[e];
  const int col = cols[e];
  const float v = vals[e];
  const unsigned b = e / epb;
  const float4 y = *(const float4*)(Y + (size_t)col * ystride + (size_t)b * yblk + lane * 4);
  float* o = out + (size_t)row * 128 + lane * 4;
  atomicAdd(o + 0, v * y.x);
  atomicAdd(o + 1, v * y.y);
  atomicAdd(o + 2, v * y.z);
  atomicAdd(o + 3, v * y.w);
}

extern "C" void kernel_launch(void* const* d_in, const int* in_sizes, int n_in,
                              void* d_out, int out_size, void* d_ws, size_t ws_size,
                              hipStream_t stream) {
  const float* X    = (const float*)d_in[0];
  const int*   rows = (const int*)d_in[1];
  const int*   cols = (const int*)d_in[2];
  const float* vals = (const float*)d_in[3];
  const float* W    = (const float*)d_in[4];
  const float* bias = (const float*)d_in[5];
  float* out = (float*)d_out;

  const int n = out_size / 128;                 // 50000
  const unsigned ntot = (unsigned)in_sizes[1];  // 3.2M flat
  const unsigned epb = ntot / 4u;
  const int nbuk = (n + 63) >> 6;               // 782

  auto align = [](size_t x) { return (x + 255) & ~(size_t)255; };
  const size_t sz_cnt    = align((size_t)nbuk * 4);
  const size_t sz_p8     = align((size_t)nbuk * 4);
  const size_t sz_px     = align((size_t)nbuk * 4);
  const size_t sz_gcur   = align((size_t)nbuk * 4);
  const size_t sz_rstart = align((size_t)(n + 1) * 4);
  const size_t sz_staged = align(((size_t)ntot + 8u * (size_t)nbuk) * 8);
  const size_t sz_ep     = align((size_t)ntot * 8);
  const size_t sz_y      = align((size_t)n * 512 * 2);
  const size_t sz_xb     = align((size_t)n * 128 * 2);
  const size_t sz_wt     = align((size_t)512 * 128 * 2);
  const size_t meta = sz_cnt + sz_p8 + sz_px + sz_gcur + sz_rstart + sz_staged + sz_ep;

  char* ws = (char*)d_ws;
  int*   cnt       = (int*)(ws);
  int*   pstart8   = (int*)(ws + sz_cnt);
  int*   pstartX   = (int*)(ws + sz_cnt + sz_p8);
  int*   gcur      = (int*)(ws + sz_cnt + sz_p8 + sz_px);
  int*   row_start = (int*)(ws + sz_cnt + sz_p8 + sz_px + sz_gcur);
  uint2* staged    = (uint2*)(ws + sz_cnt + sz_p8 + sz_px + sz_gcur + sz_rstart);
  uint2* ep        = (uint2*)(ws + meta - sz_ep);
  ushort* Y        = (ushort*)(ws + meta);
  ushort* Xb       = (ushort*)(ws + meta + sz_y);
  ushort* Wt       = (ushort*)(ws + meta + sz_y + sz_xb);

  const bool fast_ok = (n <= 65536) && (nbuk <= NBUK_MAX) && (nbuk <= 1024) &&
                       (ntot % 4u == 0u) && (in_sizes[0] == n * 128) &&
                       (in_sizes[4] == 512 * 128) &&
                       (ws_size >= meta + sz_y + sz_xb + sz_wt);

  if (fast_ok) {
    hipMemsetAsync(cnt, 0, (size_t)nbuk * 4, stream);
    hist_kernel<<<dim3(256), dim3(256), 0, stream>>>(rows, cnt, ntot, nbuk);
    scan2_kernel<<<dim3(1), dim3(1024), 0, stream>>>(
        cnt, pstart8, pstartX, gcur, row_start, nbuk, n, ntot);
    bscatter_kernel<<<dim3(BSCAT_BLOCKS), dim3(256), 0, stream>>>(
        rows, cols, vals, gcur, staged, ntot, epb, nbuk);
    reorder_kernel<<<dim3(nbuk), dim3(256), 0, stream>>>(
        cnt, pstart8, pstartX, staged, ep, row_start, n);
    const int nx8 = n * 16;
    prep_kernel<<<dim3((nx8 + 8192 + 255) / 256), dim3(256), 0, stream>>>(
        X, W, Xb, Wt, nx8);
    mfma_gemm_kernel<<<dim3(8, (n + 63) / 64), dim3(256), 0, stream>>>(
        Xb, Wt, Y, n);
    const unsigned gblk = (unsigned)((n + 3) / 4);
    gather_kernel<<<dim3(gblk), dim3(256), 0, stream>>>(
        row_start, ep, (const __hip_bfloat16*)Y, bias, out, n);
    return;
  }

  // Fallback: atomic path (fp32 vector gemm)
  {
    const int nquads = n * 32;
    init_out_kernel<<<dim3((nquads + 255) / 256), dim3(256), 0, stream>>>(out, bias, nquads);
    float* Yf = (float*)d_ws;
    const size_t need_fused = (size_t)n * 512 * sizeof(float);
    if (ws_size >= need_fused) {
      dim3 g(512 / 64, (n + 63) / 64);
      gemm_kernel<float><<<g, dim3(256), 0, stream>>>(X, W, Yf, n, 0, 512);
      const unsigned nblk = (ntot + 7) / 8;
      scatter_kernel<<<dim3(nblk), dim3(256), 0, stream>>>(
          rows, cols, vals, Yf, 512, 128, epb, ntot, out);
    } else {
      for (unsigned b = 0; b < 4; ++b) {
        dim3 g(128 / 64, (n + 63) / 64);
        gemm_kernel<float><<<g, dim3(256), 0, stream>>>(X, W, Yf, n, (int)(b * 128), 128);
        const unsigned nblk = (epb + 7) / 8;
        scatter_kernel<<<dim3(nblk), dim3(256), 0, stream>>>(
            rows + (size_t)b * epb, cols + (size_t)b * epb, vals + (size_t)b * epb,
            Yf, 128, 0, epb, epb, out);
      }
    }
  }
}

// Round 8
// 368.528 us; speedup vs baseline: 2.0347x; 1.0205x over previous
//
#include <hip/hip_runtime.h>
#include <hip/hip_bf16.h>
#include <type_traits>

// out = sum_b A_b @ (X @ W_b) + bias
// 1) hist    : LDS-aggregated bucket histogram (bucket = row>>6), int4 loads
// 2) scan2   : excl scans (8-padded -> staged regions, exact -> ep regions)
// 3) bscatter: LDS-binned scatter, single-writer 64B flushes -> staged
//              (512 blocks = 2/CU, 2048-edge tiles = half the barriers)
// 4) prep    : X -> bf16 [n][128]; W -> Wt bf16 [512 gc][128 f] (K-contig)
// 5) mfma    : Y[n,512] = Xb @ Wt^T via v_mfma_f32_16x16x32_bf16, LDS-free
// 6) reorder : per-bucket LDS counting sort -> exact row-CSR ep + row_start
// 7) gather  : one wave per row, register accumulate, 8-deep ILP

#define NBUK_MAX 800
#define RCAP 6144
#define BSCAT_BLOCKS 512

typedef __attribute__((ext_vector_type(8))) short short8;
typedef __attribute__((ext_vector_type(4))) float f32x4;

static __device__ __forceinline__ ushort f2bf(float f) {
  __hip_bfloat16 h = __float2bfloat16(f);
  return *(ushort*)&h;
}

// ---------------- prep: X->bf16, W->transposed bf16 ----------------
__global__ __launch_bounds__(256) void prep_kernel(
    const float* __restrict__ X, const float* __restrict__ W,
    ushort* __restrict__ Xb, ushort* __restrict__ Wt, int nx8)
{
  const int t = blockIdx.x * 256 + threadIdx.x;
  if (t < nx8) {
    const float4 v0 = ((const float4*)X)[t * 2];
    const float4 v1 = ((const float4*)X)[t * 2 + 1];
    ushort4 o0, o1;
    o0.x = f2bf(v0.x); o0.y = f2bf(v0.y); o0.z = f2bf(v0.z); o0.w = f2bf(v0.w);
    o1.x = f2bf(v1.x); o1.y = f2bf(v1.y); o1.z = f2bf(v1.z); o1.w = f2bf(v1.w);
    ((ushort4*)Xb)[t * 2] = o0;
    ((ushort4*)Xb)[t * 2 + 1] = o1;
  } else if (t < nx8 + 8192) {
    const int u = t - nx8;            // 512 gc * 16 chunks
    const int gc = u >> 4;
    const int f0 = (u & 15) * 8;
    const float* src = W + (size_t)((gc >> 7) * 128) * 128 + (gc & 127);
    ushort4 o0, o1;
    o0.x = f2bf(src[(size_t)(f0 + 0) * 128]);
    o0.y = f2bf(src[(size_t)(f0 + 1) * 128]);
    o0.z = f2bf(src[(size_t)(f0 + 2) * 128]);
    o0.w = f2bf(src[(size_t)(f0 + 3) * 128]);
    o1.x = f2bf(src[(size_t)(f0 + 4) * 128]);
    o1.y = f2bf(src[(size_t)(f0 + 5) * 128]);
    o1.z = f2bf(src[(size_t)(f0 + 6) * 128]);
    o1.w = f2bf(src[(size_t)(f0 + 7) * 128]);
    ((ushort4*)(Wt + (size_t)gc * 128 + f0))[0] = o0;
    ((ushort4*)(Wt + (size_t)gc * 128 + f0))[1] = o1;
  }
}

// ---------------- MFMA GEMM ----------------
__global__ __launch_bounds__(256) void mfma_gemm_kernel(
    const ushort* __restrict__ Xb, const ushort* __restrict__ Wt,
    ushort* __restrict__ Y, int n)
{
  const int w = threadIdx.x >> 6;
  const int l = threadIdx.x & 63;
  const int r16 = l & 15;
  const int kg = l >> 4;              // 0..3
  const int row0 = blockIdx.y * 64 + w * 16;
  const int c0 = blockIdx.x * 64;

  const int gra = min(row0 + r16, n - 1);
  const ushort* ap = Xb + (size_t)gra * 128 + kg * 8;
  const ushort* bp = Wt + (size_t)(c0 + r16) * 128 + kg * 8;

  f32x4 acc[4] = {};
#pragma unroll
  for (int k0 = 0; k0 < 128; k0 += 32) {
    const short8 a = *(const short8*)(ap + k0);
#pragma unroll
    for (int ct = 0; ct < 4; ++ct) {
      const short8 b = *(const short8*)(bp + (size_t)ct * 16 * 128 + k0);
      acc[ct] = __builtin_amdgcn_mfma_f32_16x16x32_bf16(a, b, acc[ct], 0, 0, 0);
    }
  }
  const int rs0 = row0 + kg * 4;
#pragma unroll
  for (int ct = 0; ct < 4; ++ct) {
    const int col = c0 + ct * 16 + r16;
#pragma unroll
    for (int r = 0; r < 4; ++r) {
      const int rs = rs0 + r;
      if (rs < n) Y[(size_t)rs * 512 + col] = f2bf(acc[ct][r]);
    }
  }
}

// ---------------- bucket histogram (int4 loads) ----------------
__global__ __launch_bounds__(256) void hist_kernel(
    const int* __restrict__ rows, int* __restrict__ cnt, unsigned ntot, int nbuk)
{
  __shared__ int lcnt[NBUK_MAX];
  for (int i = threadIdx.x; i < nbuk; i += 256) lcnt[i] = 0;
  __syncthreads();
  const unsigned nq = ntot >> 2;
  for (unsigned i = blockIdx.x * 256u + threadIdx.x; i < nq; i += gridDim.x * 256u) {
    const int4 r4 = ((const int4*)rows)[i];
    atomicAdd(&lcnt[((unsigned)r4.x) >> 6], 1);
    atomicAdd(&lcnt[((unsigned)r4.y) >> 6], 1);
    atomicAdd(&lcnt[((unsigned)r4.z) >> 6], 1);
    atomicAdd(&lcnt[((unsigned)r4.w) >> 6], 1);
  }
  __syncthreads();
  for (int i = threadIdx.x; i < nbuk; i += 256)
    if (lcnt[i]) atomicAdd(&cnt[i], lcnt[i]);
}

// ---------------- dual scans ----------------
__global__ __launch_bounds__(1024) void scan2_kernel(
    const int* __restrict__ cnt, int* __restrict__ pstart8,
    int* __restrict__ pstartX, int* __restrict__ gcur,
    int* __restrict__ row_start, int nbuk, int n, unsigned ntot)
{
  __shared__ int buf[1024];
  const int t = threadIdx.x;
  const int c = (t < nbuk) ? cnt[t] : 0;
  int v = (c + 7) & ~7;
  buf[t] = v;
  __syncthreads();
  for (int off = 1; off < 1024; off <<= 1) {
    const int add = (t >= off) ? buf[t - off] : 0;
    __syncthreads();
    buf[t] += add;
    __syncthreads();
  }
  if (t < nbuk) { pstart8[t] = buf[t] - v; gcur[t] = buf[t] - v; }
  __syncthreads();
  buf[t] = c;
  __syncthreads();
  for (int off = 1; off < 1024; off <<= 1) {
    const int add = (t >= off) ? buf[t - off] : 0;
    __syncthreads();
    buf[t] += add;
    __syncthreads();
  }
  if (t < nbuk) pstartX[t] = buf[t] - c;
  if (t == 0) row_start[n] = (int)ntot;
}

// ---------------- LDS-binned scatter ----------------
// payload: x = row<<16 | col ; y = hop<<30 | val_bits (val in [0,1) => 30 bits)
__global__ __launch_bounds__(256) void bscatter_kernel(
    const int* __restrict__ rows, const int* __restrict__ cols,
    const float* __restrict__ vals, int* __restrict__ gcur,
    uint2* __restrict__ staged, unsigned ntot, unsigned epb, int nbuk)
{
  __shared__ int bcnt[NBUK_MAX];
  __shared__ uint2 bins[NBUK_MAX * 8];
  for (int i = threadIdx.x; i < nbuk; i += 256) bcnt[i] = 0;
  __syncthreads();

  unsigned chunk = (ntot + gridDim.x - 1) / gridDim.x;
  chunk = (chunk + 7) & ~7u;                    // int4-pair alignment per block
  const unsigned beg = blockIdx.x * chunk;
  const unsigned end = (beg + chunk < ntot) ? (beg + chunk) : ntot;

  auto push = [&](unsigned r, unsigned c, unsigned hop, float v) {
    const uint2 pay = make_uint2((r << 16) | c, (hop << 30) | __float_as_uint(v));
    const int bk = (int)(r >> 6);
    const int p = atomicAdd(&bcnt[bk], 1);
    if (p < 8) bins[bk * 8 + p] = pay;
    else {  // rare intra-tile overflow: direct single write
      const int gp = atomicAdd(&gcur[bk], 1);
      staged[gp] = pay;
    }
  };

  for (unsigned base = beg; base < end; base += 2048) {
    const unsigned e0 = base + threadIdx.x * 8u;
    if (e0 + 7 < end) {
#pragma unroll
      for (int g = 0; g < 2; ++g) {
        const unsigned eg = e0 + (unsigned)g * 4u;
        const int4 r4 = *(const int4*)(rows + eg);
        const int4 c4 = *(const int4*)(cols + eg);
        const float4 v4 = *(const float4*)(vals + eg);
#pragma unroll
        for (int q = 0; q < 4; ++q) {
          const unsigned e = eg + q;
          const unsigned hop = (e >= 2u * epb) ? ((e >= 3u * epb) ? 3u : 2u)
                                               : ((e >= epb) ? 1u : 0u);
          push((unsigned)((&r4.x)[q]), (unsigned)((&c4.x)[q]), hop, (&v4.x)[q]);
        }
      }
    } else {
      for (unsigned e = e0; e < end && e < e0 + 8; ++e) {
        const unsigned hop = (e >= 2u * epb) ? ((e >= 3u * epb) ? 3u : 2u)
                                             : ((e >= epb) ? 1u : 0u);
        push((unsigned)rows[e], (unsigned)cols[e], hop, vals[e]);
      }
    }
    __syncthreads();
    for (int bk = threadIdx.x; bk < nbuk; bk += 256) {
      if (bcnt[bk] >= 8) {
        const int gp = atomicAdd(&gcur[bk], 8);
        uint2* dst = staged + gp;
#pragma unroll
        for (int q = 0; q < 8; ++q) dst[q] = bins[bk * 8 + q];
        bcnt[bk] = 0;
      }
    }
    __syncthreads();
  }
  for (int bk = threadIdx.x; bk < nbuk; bk += 256) {
    const int c = bcnt[bk];
    if (c > 0) {
      const int gp = atomicAdd(&gcur[bk], c);
      for (int q = 0; q < c; ++q) staged[gp + q] = bins[bk * 8 + q];
    }
  }
}

// ---------------- per-bucket counting sort -> exact CSR ----------------
__global__ __launch_bounds__(256) void reorder_kernel(
    const int* __restrict__ cnt, const int* __restrict__ pstart8,
    const int* __restrict__ pstartX, const uint2* __restrict__ staged,
    uint2* __restrict__ ep, int* __restrict__ row_start, int n)
{
  __shared__ int lcnt[64], lstart[64], lcur[64];
  __shared__ uint2 lbuf[RCAP];
  const int bk = blockIdx.x;
  const int c = cnt[bk];
  const int s8 = pstart8[bk];
  const int sx = pstartX[bk];

  if (threadIdx.x < 64) lcnt[threadIdx.x] = 0;
  __syncthreads();
  for (int j = threadIdx.x; j < c; j += 256)
    atomicAdd(&lcnt[(staged[s8 + j].x >> 16) & 63u], 1);
  __syncthreads();
  if (threadIdx.x == 0) {
    int a = 0;
    for (int i = 0; i < 64; ++i) { lstart[i] = a; lcur[i] = a; a += lcnt[i]; }
  }
  __syncthreads();
  if (threadIdx.x < 64) {
    const int gr = bk * 64 + threadIdx.x;
    if (gr < n) row_start[gr] = sx + lstart[threadIdx.x];
  }
  if (c <= RCAP) {
    for (int j = threadIdx.x; j < c; j += 256) {
      const uint2 p = staged[s8 + j];
      const unsigned rl = (p.x >> 16) & 63u;
      const int pos = atomicAdd(&lcur[rl], 1);
      lbuf[pos] = make_uint2((p.x & 0xFFFFu) * 512u + (p.y >> 30) * 128u,
                             p.y & 0x3FFFFFFFu);
    }
    __syncthreads();
    for (int j = threadIdx.x; j < c; j += 256) ep[sx + j] = lbuf[j];
  } else {
    for (int j = threadIdx.x; j < c; j += 256) {
      const uint2 p = staged[s8 + j];
      const unsigned rl = (p.x >> 16) & 63u;
      const int pos = atomicAdd(&lcur[rl], 1);
      ep[sx + pos] = make_uint2((p.x & 0xFFFFu) * 512u + (p.y >> 30) * 128u,
                                p.y & 0x3FFFFFFFu);
    }
  }
}

// ---------------- gather: one wave per row, 8-deep ILP ----------------
__global__ __launch_bounds__(256) void gather_kernel(
    const int* __restrict__ row_start, const uint2* __restrict__ ep,
    const __hip_bfloat16* __restrict__ Y, const float* __restrict__ bias,
    float* __restrict__ out, int n)
{
  const int wid = (int)((blockIdx.x * 256u + threadIdx.x) >> 6);
  if (wid >= n) return;
  const int lane = threadIdx.x & 63;
  const int js = row_start[wid];
  const int je = row_start[wid + 1];
  float ax = 0.f, ay = 0.f;

  auto ld = [&](uint2 p) -> float2 {
    const __hip_bfloat162 h = *(const __hip_bfloat162*)(Y + (size_t)p.x + lane * 2);
    const float v = __uint_as_float(p.y);
    return make_float2(v * __low2float(h), v * __high2float(h));
  };

  int j = js;
  for (; j + 7 < je; j += 8) {
    const uint2 p0 = ep[j],     p1 = ep[j + 1], p2 = ep[j + 2], p3 = ep[j + 3];
    const uint2 p4 = ep[j + 4], p5 = ep[j + 5], p6 = ep[j + 6], p7 = ep[j + 7];
    const float2 t0 = ld(p0), t1 = ld(p1), t2 = ld(p2), t3 = ld(p3);
    const float2 t4 = ld(p4), t5 = ld(p5), t6 = ld(p6), t7 = ld(p7);
    ax += ((t0.x + t1.x) + (t2.x + t3.x)) + ((t4.x + t5.x) + (t6.x + t7.x));
    ay += ((t0.y + t1.y) + (t2.y + t3.y)) + ((t4.y + t5.y) + (t6.y + t7.y));
  }
  for (; j < je; ++j) {
    const float2 t = ld(ep[j]);
    ax += t.x; ay += t.y;
  }
  const float2 bb = *(const float2*)(bias + lane * 2);
  *(float2*)(out + (size_t)wid * 128 + lane * 2) = make_float2(ax + bb.x, ay + bb.y);
}

// ---------------- fallback (atomic path, fp32 vector gemm) ----------------
template <typename YT>
__global__ __launch_bounds__(256, 2) void gemm_kernel(
    const float* __restrict__ X, const float* __restrict__ W,
    YT* __restrict__ Y, int n_rows, int col0, int ystride)
{
  __shared__ float Xs[64][128];
  __shared__ float Ws[128][64];
  const int tid = threadIdx.x;
  const int row0 = blockIdx.y * 64;
  {
    const int lane = tid & 31;
    const int r = tid >> 5;
#pragma unroll
    for (int i = 0; i < 8; ++i) {
      const int rr = r + i * 8;
      const int gr = row0 + rr;
      float4 v = make_float4(0.f, 0.f, 0.f, 0.f);
      if (gr < n_rows) v = ((const float4*)(X + (size_t)gr * 128))[lane];
      ((float4*)&Xs[rr][0])[lane ^ ((rr >> 2) & 7)] = v;
    }
  }
  {
    const int gc0 = col0 + blockIdx.x * 64;
    const int b = gc0 >> 7;
    const int cc0 = gc0 & 127;
    const float* Wb = W + (size_t)b * 128 * 128 + cc0;
    const int lane16 = tid & 15;
    const int f = tid >> 4;
#pragma unroll
    for (int i = 0; i < 8; ++i) {
      const int ff = f + i * 16;
      const float4 v = *(const float4*)(Wb + (size_t)ff * 128 + lane16 * 4);
      ((float4*)&Ws[ff][0])[lane16] = v;
    }
  }
  __syncthreads();
  const int tx = tid & 15;
  const int ty = tid >> 4;
  float acc[4][4] = {};
#pragma unroll 2
  for (int f0 = 0; f0 < 128; f0 += 4) {
    float4 a[4];
#pragma unroll
    for (int i = 0; i < 4; ++i) {
      const int r = ty * 4 + i;
      a[i] = ((const float4*)&Xs[r][0])[(f0 >> 2) ^ ((r >> 2) & 7)];
    }
#pragma unroll
    for (int k = 0; k < 4; ++k) {
      const float4 b = *(const float4*)&Ws[f0 + k][tx * 4];
#pragma unroll
      for (int i = 0; i < 4; ++i) {
        const float av = (&a[i].x)[k];
        acc[i][0] = fmaf(av, b.x, acc[i][0]);
        acc[i][1] = fmaf(av, b.y, acc[i][1]);
        acc[i][2] = fmaf(av, b.z, acc[i][2]);
        acc[i][3] = fmaf(av, b.w, acc[i][3]);
      }
    }
  }
  const int yc = blockIdx.x * 64 + tx * 4;
#pragma unroll
  for (int i = 0; i < 4; ++i) {
    const int gr = row0 + ty * 4 + i;
    if (gr >= n_rows) continue;
    *(float4*)(Y + (size_t)gr * ystride + yc) =
        make_float4(acc[i][0], acc[i][1], acc[i][2], acc[i][3]);
  }
}

__global__ __launch_bounds__(256) void init_out_kernel(
    float* __restrict__ out, const float* __restrict__ bias, int nquads)
{
  int i = blockIdx.x * blockDim.x + threadIdx.x;
  if (i >= nquads) return;
  const float4 b = ((const float4*)bias)[i & 31];
  ((float4*)out)[i] = b;
}

__global__ __launch_bounds__(256) void scatter_kernel(
    const int* __restrict__ rows, const int* __restrict__ cols,
    const float* __restrict__ vals, const float* __restrict__ Y,
    int ystride, int yblk, unsigned epb, unsigned ntot,
    float* __restrict__ out)
{
  const unsigned e = blockIdx.x * 8u + (threadIdx.x >> 5);
  if (e >= ntot) return;
  const int lane = threadIdx.x & 31;
  const int row = rows[e];
  const int col = cols[e];
  const float v = vals[e];
  const unsigned b = e / epb;
  const float4 y = *(const float4*)(Y + (size_t)col * ystride + (size_t)b * yblk + lane * 4);
  float* o = out + (size_t)row * 128 + lane * 4;
  atomicAdd(o + 0, v * y.x);
  atomicAdd(o + 1, v * y.y);
  atomicAdd(o + 2, v * y.z);
  atomicAdd(o + 3, v * y.w);
}

extern "C" void kernel_launch(void* const* d_in, const int* in_sizes, int n_in,
                              void* d_out, int out_size, void* d_ws, size_t ws_size,
                              hipStream_t stream) {
  const float* X    = (const float*)d_in[0];
  const int*   rows = (const int*)d_in[1];
  const int*   cols = (const int*)d_in[2];
  const float* vals = (const float*)d_in[3];
  const float* W    = (const float*)d_in[4];
  const float* bias = (const float*)d_in[5];
  float* out = (float*)d_out;

  const int n = out_size / 128;                 // 50000
  const unsigned ntot = (unsigned)in_sizes[1];  // 3.2M flat
  const unsigned epb = ntot / 4u;
  const int nbuk = (n + 63) >> 6;               // 782

  auto align = [](size_t x) { return (x + 255) & ~(size_t)255; };
  const size_t sz_cnt    = align((size_t)nbuk * 4);
  const size_t sz_p8     = align((size_t)nbuk * 4);
  const size_t sz_px     = align((size_t)nbuk * 4);
  const size_t sz_gcur   = align((size_t)nbuk * 4);
  const size_t sz_rstart = align((size_t)(n + 1) * 4);
  const size_t sz_staged = align(((size_t)ntot + 8u * (size_t)nbuk) * 8);
  const size_t sz_ep     = align((size_t)ntot * 8);
  const size_t sz_y      = align((size_t)n * 512 * 2);
  const size_t sz_xb     = align((size_t)n * 128 * 2);
  const size_t sz_wt     = align((size_t)512 * 128 * 2);
  const size_t meta = sz_cnt + sz_p8 + sz_px + sz_gcur + sz_rstart + sz_staged + sz_ep;

  char* ws = (char*)d_ws;
  int*   cnt       = (int*)(ws);
  int*   pstart8   = (int*)(ws + sz_cnt);
  int*   pstartX   = (int*)(ws + sz_cnt + sz_p8);
  int*   gcur      = (int*)(ws + sz_cnt + sz_p8 + sz_px);
  int*   row_start = (int*)(ws + sz_cnt + sz_p8 + sz_px + sz_gcur);
  uint2* staged    = (uint2*)(ws + sz_cnt + sz_p8 + sz_px + sz_gcur + sz_rstart);
  uint2* ep        = (uint2*)(ws + meta - sz_ep);
  ushort* Y        = (ushort*)(ws + meta);
  ushort* Xb       = (ushort*)(ws + meta + sz_y);
  ushort* Wt       = (ushort*)(ws + meta + sz_y + sz_xb);

  const bool fast_ok = (n <= 65536) && (nbuk <= NBUK_MAX) && (nbuk <= 1024) &&
                       (ntot % 4u == 0u) && (in_sizes[0] == n * 128) &&
                       (in_sizes[4] == 512 * 128) &&
                       (ws_size >= meta + sz_y + sz_xb + sz_wt);

  if (fast_ok) {
    hipMemsetAsync(cnt, 0, (size_t)nbuk * 4, stream);
    hist_kernel<<<dim3(512), dim3(256), 0, stream>>>(rows, cnt, ntot, nbuk);
    scan2_kernel<<<dim3(1), dim3(1024), 0, stream>>>(
        cnt, pstart8, pstartX, gcur, row_start, nbuk, n, ntot);
    bscatter_kernel<<<dim3(BSCAT_BLOCKS), dim3(256), 0, stream>>>(
        rows, cols, vals, gcur, staged, ntot, epb, nbuk);
    reorder_kernel<<<dim3(nbuk), dim3(256), 0, stream>>>(
        cnt, pstart8, pstartX, staged, ep, row_start, n);
    const int nx8 = n * 16;
    prep_kernel<<<dim3((nx8 + 8192 + 255) / 256), dim3(256), 0, stream>>>(
        X, W, Xb, Wt, nx8);
    mfma_gemm_kernel<<<dim3(8, (n + 63) / 64), dim3(256), 0, stream>>>(
        Xb, Wt, Y, n);
    const unsigned gblk = (unsigned)((n + 3) / 4);
    gather_kernel<<<dim3(gblk), dim3(256), 0, stream>>>(
        row_start, ep, (const __hip_bfloat16*)Y, bias, out, n);
    return;
  }

  // Fallback: atomic path (fp32 vector gemm)
  {
    const int nquads = n * 32;
    init_out_kernel<<<dim3((nquads + 255) / 256), dim3(256), 0, stream>>>(out, bias, nquads);
    float* Yf = (float*)d_ws;
    const size_t need_fused = (size_t)n * 512 * sizeof(float);
    if (ws_size >= need_fused) {
      dim3 g(512 / 64, (n + 63) / 64);
      gemm_kernel<float><<<g, dim3(256), 0, stream>>>(X, W, Yf, n, 0, 512);
      const unsigned nblk = (ntot + 7) / 8;
      scatter_kernel<<<dim3(nblk), dim3(256), 0, stream>>>(
          rows, cols, vals, Yf, 512, 128, epb, ntot, out);
    } else {
      for (unsigned b = 0; b < 4; ++b) {
        dim3 g(128 / 64, (n + 63) / 64);
        gemm_kernel<float><<<g, dim3(256), 0, stream>>>(X, W, Yf, n, (int)(b * 128), 128);
        const unsigned nblk = (epb + 7) / 8;
        scatter_kernel<<<dim3(nblk), dim3(256), 0, stream>>>(
            rows + (size_t)b * epb, cols + (size_t)b * epb, vals + (size_t)b * epb,
            Yf, 128, 0, epb, epb, out);
      }
    }
  }
}

// Round 9
// 263.424 us; speedup vs baseline: 2.8466x; 1.3990x over previous
//
#include <hip/hip_runtime.h>
#include <hip/hip_bf16.h>
#include <type_traits>

// out = sum_b A_b @ (X @ W_b) + bias
// 1) hist2   : per-block chunk histogram -> cnt2[blk][bk] + global cnt (fire&forget atomics)
// 2) scan2   : exclusive scan of exact counts -> pstartX; row_start[n]=ntot
// 3) scanB   : per-bucket exscan over 512 block counts -> bstart2[blk][bk]
//              (gives every (block,bucket) an exclusive exact sub-region)
// 4) bscatter2: LDS-binned scatter with PURE-LDS cursors, zero global atomics
// 5) prep    : X -> bf16; W -> Wt bf16 [512][128] (K-contig)
// 6) mfma    : Y[n,512] = Xb @ Wt^T via v_mfma_f32_16x16x32_bf16
// 7) reorder : per-bucket LDS counting sort -> exact row-CSR ep + row_start
// 8) gather  : one wave per row, register accumulate, 8-deep ILP

#define NBUK_MAX 800
#define RCAP 6144
#define NBLK 512        // blocks for hist2/bscatter2; scanB hardcodes 64x8=512

typedef __attribute__((ext_vector_type(8))) short short8;
typedef __attribute__((ext_vector_type(4))) float f32x4;

static __device__ __forceinline__ ushort f2bf(float f) {
  __hip_bfloat16 h = __float2bfloat16(f);
  return *(ushort*)&h;
}

// ---------------- hist2: per-block chunk histogram ----------------
__global__ __launch_bounds__(256) void hist2_kernel(
    const int* __restrict__ rows, int* __restrict__ cnt,
    int* __restrict__ cnt2, unsigned ntot, int nbuk, unsigned chunk)
{
  __shared__ int lcnt[NBUK_MAX];
  for (int i = threadIdx.x; i < nbuk; i += 256) lcnt[i] = 0;
  __syncthreads();
  const unsigned beg = blockIdx.x * chunk;
  const unsigned end = (beg + chunk < ntot) ? (beg + chunk) : ntot;
  if (beg < end) {
    const unsigned q0 = beg >> 2, q1 = end >> 2;   // chunk 8-aligned, ntot %4==0
    for (unsigned i = q0 + threadIdx.x; i < q1; i += 256) {
      const int4 r4 = ((const int4*)rows)[i];
      atomicAdd(&lcnt[((unsigned)r4.x) >> 6], 1);
      atomicAdd(&lcnt[((unsigned)r4.y) >> 6], 1);
      atomicAdd(&lcnt[((unsigned)r4.z) >> 6], 1);
      atomicAdd(&lcnt[((unsigned)r4.w) >> 6], 1);
    }
  }
  __syncthreads();
  int* myrow = cnt2 + (size_t)blockIdx.x * nbuk;
  for (int i = threadIdx.x; i < nbuk; i += 256) {
    const int c = lcnt[i];
    myrow[i] = c;
    if (c) atomicAdd(&cnt[i], c);   // non-returning, pipelined
  }
}

// ---------------- scan2: exact exclusive scan ----------------
__global__ __launch_bounds__(1024) void scan2_kernel(
    const int* __restrict__ cnt, int* __restrict__ pstartX,
    int* __restrict__ row_start, int nbuk, int n, unsigned ntot)
{
  __shared__ int buf[1024];
  const int t = threadIdx.x;
  const int c = (t < nbuk) ? cnt[t] : 0;
  buf[t] = c;
  __syncthreads();
  for (int off = 1; off < 1024; off <<= 1) {
    const int add = (t >= off) ? buf[t - off] : 0;
    __syncthreads();
    buf[t] += add;
    __syncthreads();
  }
  if (t < nbuk) pstartX[t] = buf[t] - c;
  if (t == 0) row_start[n] = (int)ntot;
}

// ---------------- scanB: per-bucket exscan over 512 block counts ----------
// wave per bucket; lane l handles blocks l*8..l*8+7
__global__ __launch_bounds__(256) void scanB_kernel(
    const int* __restrict__ cnt2, const int* __restrict__ pstartX,
    int* __restrict__ bstart2, int nbuk)
{
  const int bk = blockIdx.x * 4 + (threadIdx.x >> 6);
  if (bk >= nbuk) return;
  const int lane = threadIdx.x & 63;
  int v[8];
  int lanesum = 0;
#pragma unroll
  for (int i = 0; i < 8; ++i) {
    v[i] = cnt2[(size_t)(lane * 8 + i) * nbuk + bk];
    lanesum += v[i];
  }
  int incl = lanesum;
#pragma unroll
  for (int off = 1; off < 64; off <<= 1) {
    const int t = __shfl_up(incl, off);
    if (lane >= off) incl += t;
  }
  int run = pstartX[bk] + (incl - lanesum);
#pragma unroll
  for (int i = 0; i < 8; ++i) {
    bstart2[(size_t)(lane * 8 + i) * nbuk + bk] = run;
    run += v[i];
  }
}

// ---------------- bscatter2: LDS bins, pure-LDS cursors ----------------
// payload: x = row<<16 | col ; y = hop<<30 | val_bits (val in [0,1) => 30 bits)
__global__ __launch_bounds__(256) void bscatter2_kernel(
    const int* __restrict__ rows, const int* __restrict__ cols,
    const float* __restrict__ vals, const int* __restrict__ bstart2,
    uint2* __restrict__ staged, unsigned ntot, unsigned epb, int nbuk,
    unsigned chunk)
{
  __shared__ int bcnt[NBUK_MAX];
  __shared__ int lcur[NBUK_MAX];
  __shared__ uint2 bins[NBUK_MAX * 8];
  {
    const int* myrow = bstart2 + (size_t)blockIdx.x * nbuk;
    for (int i = threadIdx.x; i < nbuk; i += 256) {
      bcnt[i] = 0;
      lcur[i] = myrow[i];
    }
  }
  __syncthreads();

  const unsigned beg = blockIdx.x * chunk;
  const unsigned end = (beg + chunk < ntot) ? (beg + chunk) : ntot;

  auto push = [&](unsigned r, unsigned c, unsigned hop, float v) {
    const uint2 pay = make_uint2((r << 16) | c, (hop << 30) | __float_as_uint(v));
    const int bk = (int)(r >> 6);
    const int p = atomicAdd(&bcnt[bk], 1);
    if (p < 8) bins[bk * 8 + p] = pay;
    else {  // rare intra-tile overflow: allocate slot from LDS cursor
      const int gp = atomicAdd(&lcur[bk], 1);
      staged[gp] = pay;
    }
  };

  for (unsigned base = beg; base < end; base += 2048) {
    const unsigned e0 = base + threadIdx.x * 8u;
    if (e0 + 7 < end) {
#pragma unroll
      for (int g = 0; g < 2; ++g) {
        const unsigned eg = e0 + (unsigned)g * 4u;
        const int4 r4 = *(const int4*)(rows + eg);
        const int4 c4 = *(const int4*)(cols + eg);
        const float4 v4 = *(const float4*)(vals + eg);
#pragma unroll
        for (int q = 0; q < 4; ++q) {
          const unsigned e = eg + q;
          const unsigned hop = (e >= 2u * epb) ? ((e >= 3u * epb) ? 3u : 2u)
                                               : ((e >= epb) ? 1u : 0u);
          push((unsigned)((&r4.x)[q]), (unsigned)((&c4.x)[q]), hop, (&v4.x)[q]);
        }
      }
    } else {
      for (unsigned e = e0; e < end && e < e0 + 8; ++e) {
        const unsigned hop = (e >= 2u * epb) ? ((e >= 3u * epb) ? 3u : 2u)
                                             : ((e >= epb) ? 1u : 0u);
        push((unsigned)rows[e], (unsigned)cols[e], hop, vals[e]);
      }
    }
    __syncthreads();
    for (int bk = threadIdx.x; bk < nbuk; bk += 256) {
      if (bcnt[bk] >= 8) {             // single writer per bucket, no atomics
        const int gp = lcur[bk];
        uint2* dst = staged + gp;
#pragma unroll
        for (int q = 0; q < 8; ++q) dst[q] = bins[bk * 8 + q];
        lcur[bk] = gp + 8;
        bcnt[bk] = 0;
      }
    }
    __syncthreads();
  }
  for (int bk = threadIdx.x; bk < nbuk; bk += 256) {
    const int c = bcnt[bk];
    if (c > 0) {
      const int gp = lcur[bk];
      for (int q = 0; q < c; ++q) staged[gp + q] = bins[bk * 8 + q];
    }
  }
}

// ---------------- prep: X->bf16, W->transposed bf16 ----------------
__global__ __launch_bounds__(256) void prep_kernel(
    const float* __restrict__ X, const float* __restrict__ W,
    ushort* __restrict__ Xb, ushort* __restrict__ Wt, int nx8)
{
  const int t = blockIdx.x * 256 + threadIdx.x;
  if (t < nx8) {
    const float4 v0 = ((const float4*)X)[t * 2];
    const float4 v1 = ((const float4*)X)[t * 2 + 1];
    ushort4 o0, o1;
    o0.x = f2bf(v0.x); o0.y = f2bf(v0.y); o0.z = f2bf(v0.z); o0.w = f2bf(v0.w);
    o1.x = f2bf(v1.x); o1.y = f2bf(v1.y); o1.z = f2bf(v1.z); o1.w = f2bf(v1.w);
    ((ushort4*)Xb)[t * 2] = o0;
    ((ushort4*)Xb)[t * 2 + 1] = o1;
  } else if (t < nx8 + 8192) {
    const int u = t - nx8;
    const int gc = u >> 4;
    const int f0 = (u & 15) * 8;
    const float* src = W + (size_t)((gc >> 7) * 128) * 128 + (gc & 127);
    ushort4 o0, o1;
    o0.x = f2bf(src[(size_t)(f0 + 0) * 128]);
    o0.y = f2bf(src[(size_t)(f0 + 1) * 128]);
    o0.z = f2bf(src[(size_t)(f0 + 2) * 128]);
    o0.w = f2bf(src[(size_t)(f0 + 3) * 128]);
    o1.x = f2bf(src[(size_t)(f0 + 4) * 128]);
    o1.y = f2bf(src[(size_t)(f0 + 5) * 128]);
    o1.z = f2bf(src[(size_t)(f0 + 6) * 128]);
    o1.w = f2bf(src[(size_t)(f0 + 7) * 128]);
    ((ushort4*)(Wt + (size_t)gc * 128 + f0))[0] = o0;
    ((ushort4*)(Wt + (size_t)gc * 128 + f0))[1] = o1;
  }
}

// ---------------- MFMA GEMM ----------------
__global__ __launch_bounds__(256) void mfma_gemm_kernel(
    const ushort* __restrict__ Xb, const ushort* __restrict__ Wt,
    ushort* __restrict__ Y, int n)
{
  const int w = threadIdx.x >> 6;
  const int l = threadIdx.x & 63;
  const int r16 = l & 15;
  const int kg = l >> 4;
  const int row0 = blockIdx.y * 64 + w * 16;
  const int c0 = blockIdx.x * 64;

  const int gra = min(row0 + r16, n - 1);
  const ushort* ap = Xb + (size_t)gra * 128 + kg * 8;
  const ushort* bp = Wt + (size_t)(c0 + r16) * 128 + kg * 8;

  f32x4 acc[4] = {};
#pragma unroll
  for (int k0 = 0; k0 < 128; k0 += 32) {
    const short8 a = *(const short8*)(ap + k0);
#pragma unroll
    for (int ct = 0; ct < 4; ++ct) {
      const short8 b = *(const short8*)(bp + (size_t)ct * 16 * 128 + k0);
      acc[ct] = __builtin_amdgcn_mfma_f32_16x16x32_bf16(a, b, acc[ct], 0, 0, 0);
    }
  }
  const int rs0 = row0 + kg * 4;
#pragma unroll
  for (int ct = 0; ct < 4; ++ct) {
    const int col = c0 + ct * 16 + r16;
#pragma unroll
    for (int r = 0; r < 4; ++r) {
      const int rs = rs0 + r;
      if (rs < n) Y[(size_t)rs * 512 + col] = f2bf(acc[ct][r]);
    }
  }
}

// ---------------- per-bucket counting sort -> exact CSR ----------------
__global__ __launch_bounds__(256) void reorder_kernel(
    const int* __restrict__ cnt, const int* __restrict__ pstartX,
    const uint2* __restrict__ staged, uint2* __restrict__ ep,
    int* __restrict__ row_start, int n)
{
  __shared__ int lcnt[64], lstart[64], lcur[64];
  __shared__ uint2 lbuf[RCAP];
  const int bk = blockIdx.x;
  const int c = cnt[bk];
  const int sx = pstartX[bk];

  if (threadIdx.x < 64) lcnt[threadIdx.x] = 0;
  __syncthreads();
  for (int j = threadIdx.x; j < c; j += 256)
    atomicAdd(&lcnt[(staged[sx + j].x >> 16) & 63u], 1);
  __syncthreads();
  if (threadIdx.x == 0) {
    int a = 0;
    for (int i = 0; i < 64; ++i) { lstart[i] = a; lcur[i] = a; a += lcnt[i]; }
  }
  __syncthreads();
  if (threadIdx.x < 64) {
    const int gr = bk * 64 + threadIdx.x;
    if (gr < n) row_start[gr] = sx + lstart[threadIdx.x];
  }
  if (c <= RCAP) {
    for (int j = threadIdx.x; j < c; j += 256) {
      const uint2 p = staged[sx + j];
      const unsigned rl = (p.x >> 16) & 63u;
      const int pos = atomicAdd(&lcur[rl], 1);
      lbuf[pos] = make_uint2((p.x & 0xFFFFu) * 512u + (p.y >> 30) * 128u,
                             p.y & 0x3FFFFFFFu);
    }
    __syncthreads();
    for (int j = threadIdx.x; j < c; j += 256) ep[sx + j] = lbuf[j];
  } else {
    for (int j = threadIdx.x; j < c; j += 256) {
      const uint2 p = staged[sx + j];
      const unsigned rl = (p.x >> 16) & 63u;
      const int pos = atomicAdd(&lcur[rl], 1);
      ep[sx + pos] = make_uint2((p.x & 0xFFFFu) * 512u + (p.y >> 30) * 128u,
                                p.y & 0x3FFFFFFFu);
    }
  }
}

// ---------------- gather: one wave per row, 8-deep ILP ----------------
__global__ __launch_bounds__(256) void gather_kernel(
    const int* __restrict__ row_start, const uint2* __restrict__ ep,
    const __hip_bfloat16* __restrict__ Y, const float* __restrict__ bias,
    float* __restrict__ out, int n)
{
  const int wid = (int)((blockIdx.x * 256u + threadIdx.x) >> 6);
  if (wid >= n) return;
  const int lane = threadIdx.x & 63;
  const int js = row_start[wid];
  const int je = row_start[wid + 1];
  float ax = 0.f, ay = 0.f;

  auto ld = [&](uint2 p) -> float2 {
    const __hip_bfloat162 h = *(const __hip_bfloat162*)(Y + (size_t)p.x + lane * 2);
    const float v = __uint_as_float(p.y);
    return make_float2(v * __low2float(h), v * __high2float(h));
  };

  int j = js;
  for (; j + 7 < je; j += 8) {
    const uint2 p0 = ep[j],     p1 = ep[j + 1], p2 = ep[j + 2], p3 = ep[j + 3];
    const uint2 p4 = ep[j + 4], p5 = ep[j + 5], p6 = ep[j + 6], p7 = ep[j + 7];
    const float2 t0 = ld(p0), t1 = ld(p1), t2 = ld(p2), t3 = ld(p3);
    const float2 t4 = ld(p4), t5 = ld(p5), t6 = ld(p6), t7 = ld(p7);
    ax += ((t0.x + t1.x) + (t2.x + t3.x)) + ((t4.x + t5.x) + (t6.x + t7.x));
    ay += ((t0.y + t1.y) + (t2.y + t3.y)) + ((t4.y + t5.y) + (t6.y + t7.y));
  }
  for (; j < je; ++j) {
    const float2 t = ld(ep[j]);
    ax += t.x; ay += t.y;
  }
  const float2 bb = *(const float2*)(bias + lane * 2);
  *(float2*)(out + (size_t)wid * 128 + lane * 2) = make_float2(ax + bb.x, ay + bb.y);
}

// ---------------- fallback (atomic path, fp32 vector gemm) ----------------
template <typename YT>
__global__ __launch_bounds__(256, 2) void gemm_kernel(
    const float* __restrict__ X, const float* __restrict__ W,
    YT* __restrict__ Y, int n_rows, int col0, int ystride)
{
  __shared__ float Xs[64][128];
  __shared__ float Ws[128][64];
  const int tid = threadIdx.x;
  const int row0 = blockIdx.y * 64;
  {
    const int lane = tid & 31;
    const int r = tid >> 5;
#pragma unroll
    for (int i = 0; i < 8; ++i) {
      const int rr = r + i * 8;
      const int gr = row0 + rr;
      float4 v = make_float4(0.f, 0.f, 0.f, 0.f);
      if (gr < n_rows) v = ((const float4*)(X + (size_t)gr * 128))[lane];
      ((float4*)&Xs[rr][0])[lane ^ ((rr >> 2) & 7)] = v;
    }
  }
  {
    const int gc0 = col0 + blockIdx.x * 64;
    const int b = gc0 >> 7;
    const int cc0 = gc0 & 127;
    const float* Wb = W + (size_t)b * 128 * 128 + cc0;
    const int lane16 = tid & 15;
    const int f = tid >> 4;
#pragma unroll
    for (int i = 0; i < 8; ++i) {
      const int ff = f + i * 16;
      const float4 v = *(const float4*)(Wb + (size_t)ff * 128 + lane16 * 4);
      ((float4*)&Ws[ff][0])[lane16] = v;
    }
  }
  __syncthreads();
  const int tx = tid & 15;
  const int ty = tid >> 4;
  float acc[4][4] = {};
#pragma unroll 2
  for (int f0 = 0; f0 < 128; f0 += 4) {
    float4 a[4];
#pragma unroll
    for (int i = 0; i < 4; ++i) {
      const int r = ty * 4 + i;
      a[i] = ((const float4*)&Xs[r][0])[(f0 >> 2) ^ ((r >> 2) & 7)];
    }
#pragma unroll
    for (int k = 0; k < 4; ++k) {
      const float4 b = *(const float4*)&Ws[f0 + k][tx * 4];
#pragma unroll
      for (int i = 0; i < 4; ++i) {
        const float av = (&a[i].x)[k];
        acc[i][0] = fmaf(av, b.x, acc[i][0]);
        acc[i][1] = fmaf(av, b.y, acc[i][1]);
        acc[i][2] = fmaf(av, b.z, acc[i][2]);
        acc[i][3] = fmaf(av, b.w, acc[i][3]);
      }
    }
  }
  const int yc = blockIdx.x * 64 + tx * 4;
#pragma unroll
  for (int i = 0; i < 4; ++i) {
    const int gr = row0 + ty * 4 + i;
    if (gr >= n_rows) continue;
    *(float4*)(Y + (size_t)gr * ystride + yc) =
        make_float4(acc[i][0], acc[i][1], acc[i][2], acc[i][3]);
  }
}

__global__ __launch_bounds__(256) void init_out_kernel(
    float* __restrict__ out, const float* __restrict__ bias, int nquads)
{
  int i = blockIdx.x * blockDim.x + threadIdx.x;
  if (i >= nquads) return;
  const float4 b = ((const float4*)bias)[i & 31];
  ((float4*)out)[i] = b;
}

__global__ __launch_bounds__(256) void scatter_kernel(
    const int* __restrict__ rows, const int* __restrict__ cols,
    const float* __restrict__ vals, const float* __restrict__ Y,
    int ystride, int yblk, unsigned epb, unsigned ntot,
    float* __restrict__ out)
{
  const unsigned e = blockIdx.x * 8u + (threadIdx.x >> 5);
  if (e >= ntot) return;
  const int lane = threadIdx.x & 31;
  const int row = rows[e];
  const int col = cols[e];
  const float v = vals[e];
  const unsigned b = e / epb;
  const float4 y = *(const float4*)(Y + (size_t)col * ystride + (size_t)b * yblk + lane * 4);
  float* o = out + (size_t)row * 128 + lane * 4;
  atomicAdd(o + 0, v * y.x);
  atomicAdd(o + 1, v * y.y);
  atomicAdd(o + 2, v * y.z);
  atomicAdd(o + 3, v * y.w);
}

extern "C" void kernel_launch(void* const* d_in, const int* in_sizes, int n_in,
                              void* d_out, int out_size, void* d_ws, size_t ws_size,
                              hipStream_t stream) {
  const float* X    = (const float*)d_in[0];
  const int*   rows = (const int*)d_in[1];
  const int*   cols = (const int*)d_in[2];
  const float* vals = (const float*)d_in[3];
  const float* W    = (const float*)d_in[4];
  const float* bias = (const float*)d_in[5];
  float* out = (float*)d_out;

  const int n = out_size / 128;                 // 50000
  const unsigned ntot = (unsigned)in_sizes[1];  // 3.2M flat
  const unsigned epb = ntot / 4u;
  const int nbuk = (n + 63) >> 6;               // 782

  auto align = [](size_t x) { return (x + 255) & ~(size_t)255; };
  const size_t sz_cnt    = align((size_t)nbuk * 4);
  const size_t sz_px     = align((size_t)nbuk * 4);
  const size_t sz_rstart = align((size_t)(n + 1) * 4);
  const size_t sz_cnt2   = align((size_t)NBLK * nbuk * 4);
  const size_t sz_bst2   = align((size_t)NBLK * nbuk * 4);
  const size_t sz_staged = align((size_t)ntot * 8 + 256);
  const size_t sz_ep     = align((size_t)ntot * 8);
  const size_t sz_y      = align((size_t)n * 512 * 2);
  const size_t sz_xb     = align((size_t)n * 128 * 2);
  const size_t sz_wt     = align((size_t)512 * 128 * 2);
  const size_t meta = sz_cnt + sz_px + sz_rstart + sz_cnt2 + sz_bst2 + sz_staged + sz_ep;

  char* ws = (char*)d_ws;
  int*   cnt       = (int*)(ws);
  int*   pstartX   = (int*)(ws + sz_cnt);
  int*   row_start = (int*)(ws + sz_cnt + sz_px);
  int*   cnt2      = (int*)(ws + sz_cnt + sz_px + sz_rstart);
  int*   bstart2   = (int*)(ws + sz_cnt + sz_px + sz_rstart + sz_cnt2);
  uint2* staged    = (uint2*)(ws + sz_cnt + sz_px + sz_rstart + sz_cnt2 + sz_bst2);
  uint2* ep        = (uint2*)(ws + meta - sz_ep);
  ushort* Y        = (ushort*)(ws + meta);
  ushort* Xb       = (ushort*)(ws + meta + sz_y);
  ushort* Wt       = (ushort*)(ws + meta + sz_y + sz_xb);

  const bool fast_ok = (n <= 65536) && (nbuk <= NBUK_MAX) && (nbuk <= 1024) &&
                       (ntot % 4u == 0u) && (in_sizes[0] == n * 128) &&
                       (in_sizes[4] == 512 * 128) &&
                       (ws_size >= meta + sz_y + sz_xb + sz_wt);

  if (fast_ok) {
    const unsigned chunk = (((ntot + NBLK - 1u) / NBLK) + 7u) & ~7u;
    hipMemsetAsync(cnt, 0, (size_t)nbuk * 4, stream);
    hist2_kernel<<<dim3(NBLK), dim3(256), 0, stream>>>(
        rows, cnt, cnt2, ntot, nbuk, chunk);
    scan2_kernel<<<dim3(1), dim3(1024), 0, stream>>>(
        cnt, pstartX, row_start, nbuk, n, ntot);
    scanB_kernel<<<dim3((nbuk + 3) / 4), dim3(256), 0, stream>>>(
        cnt2, pstartX, bstart2, nbuk);
    bscatter2_kernel<<<dim3(NBLK), dim3(256), 0, stream>>>(
        rows, cols, vals, bstart2, staged, ntot, epb, nbuk, chunk);
    reorder_kernel<<<dim3(nbuk), dim3(256), 0, stream>>>(
        cnt, pstartX, staged, ep, row_start, n);
    const int nx8 = n * 16;
    prep_kernel<<<dim3((nx8 + 8192 + 255) / 256), dim3(256), 0, stream>>>(
        X, W, Xb, Wt, nx8);
    mfma_gemm_kernel<<<dim3(8, (n + 63) / 64), dim3(256), 0, stream>>>(
        Xb, Wt, Y, n);
    const unsigned gblk = (unsigned)((n + 3) / 4);
    gather_kernel<<<dim3(gblk), dim3(256), 0, stream>>>(
        row_start, ep, (const __hip_bfloat16*)Y, bias, out, n);
    return;
  }

  // Fallback: atomic path (fp32 vector gemm)
  {
    const int nquads = n * 32;
    init_out_kernel<<<dim3((nquads + 255) / 256), dim3(256), 0, stream>>>(out, bias, nquads);
    float* Yf = (float*)d_ws;
    const size_t need_fused = (size_t)n * 512 * sizeof(float);
    if (ws_size >= need_fused) {
      dim3 g(512 / 64, (n + 63) / 64);
      gemm_kernel<float><<<g, dim3(256), 0, stream>>>(X, W, Yf, n, 0, 512);
      const unsigned nblk = (ntot + 7) / 8;
      scatter_kernel<<<dim3(nblk), dim3(256), 0, stream>>>(
          rows, cols, vals, Yf, 512, 128, epb, ntot, out);
    } else {
      for (unsigned b = 0; b < 4; ++b) {
        dim3 g(128 / 64, (n + 63) / 64);
        gemm_kernel<float><<<g, dim3(256), 0, stream>>>(X, W, Yf, n, (int)(b * 128), 128);
        const unsigned nblk = (epb + 7) / 8;
        scatter_kernel<<<dim3(nblk), dim3(256), 0, stream>>>(
            rows + (size_t)b * epb, cols + (size_t)b * epb, vals + (size_t)b * epb,
            Yf, 128, 0, epb, epb, out);
      }
    }
  }
}

// Round 10
// 249.040 us; speedup vs baseline: 3.0110x; 1.0578x over previous
//
#include <hip/hip_runtime.h>
#include <hip/hip_bf16.h>
#include <type_traits>

// out = sum_b A_b @ (X @ W_b) + bias
// 1) hist2   : per-block chunk histogram -> cnt2[blk][bk] + global cnt
// 2) scan2   : exclusive scan of exact counts -> pstartX; row_start[n]=ntot
// 3) scanB   : per-bucket exscan over 512 block counts -> bstart2[blk][bk]
// 4) bscatter2: LDS-binned scatter with pure-LDS cursors, zero global atomics
// 5) prep    : X -> bf16; W -> Wt bf16 [512][128] (K-contig)
// 6) mfma    : Y[n,512] = Xb @ Wt^T via v_mfma_f32_16x16x32_bf16
// 7) reorder : per-bucket LDS counting sort -> row-CSR ep (PACKED 4B) + row_start
//              ep = (val_q14 << 18) | (col*4 + hop); yoff = low18 * 128
// 8) gather  : wave per row, PAIRED edges (half-wave each), 8B Y loads/lane

#define NBUK_MAX 800
#define RCAP 8192
#define NBLK 512        // blocks for hist2/bscatter2; scanB hardcodes 64x8=512

typedef __attribute__((ext_vector_type(8))) short short8;
typedef __attribute__((ext_vector_type(4))) float f32x4;

static __device__ __forceinline__ ushort f2bf(float f) {
  __hip_bfloat16 h = __float2bfloat16(f);
  return *(ushort*)&h;
}
static __device__ __forceinline__ float bf2f(ushort u) {
  return __uint_as_float(((unsigned)u) << 16);
}

// ---------------- hist2: per-block chunk histogram ----------------
__global__ __launch_bounds__(256) void hist2_kernel(
    const int* __restrict__ rows, int* __restrict__ cnt,
    int* __restrict__ cnt2, unsigned ntot, int nbuk, unsigned chunk)
{
  __shared__ int lcnt[NBUK_MAX];
  for (int i = threadIdx.x; i < nbuk; i += 256) lcnt[i] = 0;
  __syncthreads();
  const unsigned beg = blockIdx.x * chunk;
  const unsigned end = (beg + chunk < ntot) ? (beg + chunk) : ntot;
  if (beg < end) {
    const unsigned q0 = beg >> 2, q1 = end >> 2;
    for (unsigned i = q0 + threadIdx.x; i < q1; i += 256) {
      const int4 r4 = ((const int4*)rows)[i];
      atomicAdd(&lcnt[((unsigned)r4.x) >> 6], 1);
      atomicAdd(&lcnt[((unsigned)r4.y) >> 6], 1);
      atomicAdd(&lcnt[((unsigned)r4.z) >> 6], 1);
      atomicAdd(&lcnt[((unsigned)r4.w) >> 6], 1);
    }
  }
  __syncthreads();
  int* myrow = cnt2 + (size_t)blockIdx.x * nbuk;
  for (int i = threadIdx.x; i < nbuk; i += 256) {
    const int c = lcnt[i];
    myrow[i] = c;
    if (c) atomicAdd(&cnt[i], c);
  }
}

// ---------------- scan2: exact exclusive scan ----------------
__global__ __launch_bounds__(1024) void scan2_kernel(
    const int* __restrict__ cnt, int* __restrict__ pstartX,
    int* __restrict__ row_start, int nbuk, int n, unsigned ntot)
{
  __shared__ int buf[1024];
  const int t = threadIdx.x;
  const int c = (t < nbuk) ? cnt[t] : 0;
  buf[t] = c;
  __syncthreads();
  for (int off = 1; off < 1024; off <<= 1) {
    const int add = (t >= off) ? buf[t - off] : 0;
    __syncthreads();
    buf[t] += add;
    __syncthreads();
  }
  if (t < nbuk) pstartX[t] = buf[t] - c;
  if (t == 0) row_start[n] = (int)ntot;
}

// ---------------- scanB: per-bucket exscan over 512 block counts ----------
__global__ __launch_bounds__(256) void scanB_kernel(
    const int* __restrict__ cnt2, const int* __restrict__ pstartX,
    int* __restrict__ bstart2, int nbuk)
{
  const int bk = blockIdx.x * 4 + (threadIdx.x >> 6);
  if (bk >= nbuk) return;
  const int lane = threadIdx.x & 63;
  int v[8];
  int lanesum = 0;
#pragma unroll
  for (int i = 0; i < 8; ++i) {
    v[i] = cnt2[(size_t)(lane * 8 + i) * nbuk + bk];
    lanesum += v[i];
  }
  int incl = lanesum;
#pragma unroll
  for (int off = 1; off < 64; off <<= 1) {
    const int t = __shfl_up(incl, off);
    if (lane >= off) incl += t;
  }
  int run = pstartX[bk] + (incl - lanesum);
#pragma unroll
  for (int i = 0; i < 8; ++i) {
    bstart2[(size_t)(lane * 8 + i) * nbuk + bk] = run;
    run += v[i];
  }
}

// ---------------- bscatter2: LDS bins, pure-LDS cursors ----------------
// payload: x = row<<16 | col ; y = hop<<30 | val_bits (val in [0,1) => 30 bits)
__global__ __launch_bounds__(256) void bscatter2_kernel(
    const int* __restrict__ rows, const int* __restrict__ cols,
    const float* __restrict__ vals, const int* __restrict__ bstart2,
    uint2* __restrict__ staged, unsigned ntot, unsigned epb, int nbuk,
    unsigned chunk)
{
  __shared__ int bcnt[NBUK_MAX];
  __shared__ int lcur[NBUK_MAX];
  __shared__ uint2 bins[NBUK_MAX * 8];
  {
    const int* myrow = bstart2 + (size_t)blockIdx.x * nbuk;
    for (int i = threadIdx.x; i < nbuk; i += 256) {
      bcnt[i] = 0;
      lcur[i] = myrow[i];
    }
  }
  __syncthreads();

  const unsigned beg = blockIdx.x * chunk;
  const unsigned end = (beg + chunk < ntot) ? (beg + chunk) : ntot;

  auto push = [&](unsigned r, unsigned c, unsigned hop, float v) {
    const uint2 pay = make_uint2((r << 16) | c, (hop << 30) | __float_as_uint(v));
    const int bk = (int)(r >> 6);
    const int p = atomicAdd(&bcnt[bk], 1);
    if (p < 8) bins[bk * 8 + p] = pay;
    else {
      const int gp = atomicAdd(&lcur[bk], 1);
      staged[gp] = pay;
    }
  };

  for (unsigned base = beg; base < end; base += 2048) {
    const unsigned e0 = base + threadIdx.x * 8u;
    if (e0 + 7 < end) {
#pragma unroll
      for (int g = 0; g < 2; ++g) {
        const unsigned eg = e0 + (unsigned)g * 4u;
        const int4 r4 = *(const int4*)(rows + eg);
        const int4 c4 = *(const int4*)(cols + eg);
        const float4 v4 = *(const float4*)(vals + eg);
#pragma unroll
        for (int q = 0; q < 4; ++q) {
          const unsigned e = eg + q;
          const unsigned hop = (e >= 2u * epb) ? ((e >= 3u * epb) ? 3u : 2u)
                                               : ((e >= epb) ? 1u : 0u);
          push((unsigned)((&r4.x)[q]), (unsigned)((&c4.x)[q]), hop, (&v4.x)[q]);
        }
      }
    } else {
      for (unsigned e = e0; e < end && e < e0 + 8; ++e) {
        const unsigned hop = (e >= 2u * epb) ? ((e >= 3u * epb) ? 3u : 2u)
                                             : ((e >= epb) ? 1u : 0u);
        push((unsigned)rows[e], (unsigned)cols[e], hop, vals[e]);
      }
    }
    __syncthreads();
    for (int bk = threadIdx.x; bk < nbuk; bk += 256) {
      if (bcnt[bk] >= 8) {
        const int gp = lcur[bk];
        uint2* dst = staged + gp;
#pragma unroll
        for (int q = 0; q < 8; ++q) dst[q] = bins[bk * 8 + q];
        lcur[bk] = gp + 8;
        bcnt[bk] = 0;
      }
    }
    __syncthreads();
  }
  for (int bk = threadIdx.x; bk < nbuk; bk += 256) {
    const int c = bcnt[bk];
    if (c > 0) {
      const int gp = lcur[bk];
      for (int q = 0; q < c; ++q) staged[gp + q] = bins[bk * 8 + q];
    }
  }
}

// ---------------- prep: X->bf16, W->transposed bf16 ----------------
__global__ __launch_bounds__(256) void prep_kernel(
    const float* __restrict__ X, const float* __restrict__ W,
    ushort* __restrict__ Xb, ushort* __restrict__ Wt, int nx8)
{
  const int t = blockIdx.x * 256 + threadIdx.x;
  if (t < nx8) {
    const float4 v0 = ((const float4*)X)[t * 2];
    const float4 v1 = ((const float4*)X)[t * 2 + 1];
    ushort4 o0, o1;
    o0.x = f2bf(v0.x); o0.y = f2bf(v0.y); o0.z = f2bf(v0.z); o0.w = f2bf(v0.w);
    o1.x = f2bf(v1.x); o1.y = f2bf(v1.y); o1.z = f2bf(v1.z); o1.w = f2bf(v1.w);
    ((ushort4*)Xb)[t * 2] = o0;
    ((ushort4*)Xb)[t * 2 + 1] = o1;
  } else if (t < nx8 + 8192) {
    const int u = t - nx8;
    const int gc = u >> 4;
    const int f0 = (u & 15) * 8;
    const float* src = W + (size_t)((gc >> 7) * 128) * 128 + (gc & 127);
    ushort4 o0, o1;
    o0.x = f2bf(src[(size_t)(f0 + 0) * 128]);
    o0.y = f2bf(src[(size_t)(f0 + 1) * 128]);
    o0.z = f2bf(src[(size_t)(f0 + 2) * 128]);
    o0.w = f2bf(src[(size_t)(f0 + 3) * 128]);
    o1.x = f2bf(src[(size_t)(f0 + 4) * 128]);
    o1.y = f2bf(src[(size_t)(f0 + 5) * 128]);
    o1.z = f2bf(src[(size_t)(f0 + 6) * 128]);
    o1.w = f2bf(src[(size_t)(f0 + 7) * 128]);
    ((ushort4*)(Wt + (size_t)gc * 128 + f0))[0] = o0;
    ((ushort4*)(Wt + (size_t)gc * 128 + f0))[1] = o1;
  }
}

// ---------------- MFMA GEMM ----------------
__global__ __launch_bounds__(256) void mfma_gemm_kernel(
    const ushort* __restrict__ Xb, const ushort* __restrict__ Wt,
    ushort* __restrict__ Y, int n)
{
  const int w = threadIdx.x >> 6;
  const int l = threadIdx.x & 63;
  const int r16 = l & 15;
  const int kg = l >> 4;
  const int row0 = blockIdx.y * 64 + w * 16;
  const int c0 = blockIdx.x * 64;

  const int gra = min(row0 + r16, n - 1);
  const ushort* ap = Xb + (size_t)gra * 128 + kg * 8;
  const ushort* bp = Wt + (size_t)(c0 + r16) * 128 + kg * 8;

  f32x4 acc[4] = {};
#pragma unroll
  for (int k0 = 0; k0 < 128; k0 += 32) {
    const short8 a = *(const short8*)(ap + k0);
#pragma unroll
    for (int ct = 0; ct < 4; ++ct) {
      const short8 b = *(const short8*)(bp + (size_t)ct * 16 * 128 + k0);
      acc[ct] = __builtin_amdgcn_mfma_f32_16x16x32_bf16(a, b, acc[ct], 0, 0, 0);
    }
  }
  const int rs0 = row0 + kg * 4;
#pragma unroll
  for (int ct = 0; ct < 4; ++ct) {
    const int col = c0 + ct * 16 + r16;
#pragma unroll
    for (int r = 0; r < 4; ++r) {
      const int rs = rs0 + r;
      if (rs < n) Y[(size_t)rs * 512 + col] = f2bf(acc[ct][r]);
    }
  }
}

// ---------------- reorder: counting sort -> packed 4B ep ----------------
// ep word = (val_q14 << 18) | (col*4 + hop);  yoff = (word & 0x3FFFF) * 128
static __device__ __forceinline__ unsigned pack_ep(uint2 p) {
  const unsigned col = p.x & 0xFFFFu;
  const unsigned hop = p.y >> 30;
  const float v = __uint_as_float(p.y & 0x3FFFFFFFu);
  const unsigned vq = (unsigned)(v * 16383.f + 0.5f);
  return (vq << 18) | (col * 4u + hop);
}

__global__ __launch_bounds__(256) void reorder_kernel(
    const int* __restrict__ cnt, const int* __restrict__ pstartX,
    const uint2* __restrict__ staged, unsigned* __restrict__ ep,
    int* __restrict__ row_start, int n)
{
  __shared__ int lcnt[64], lstart[64], lcur[64];
  __shared__ unsigned lbuf[RCAP];
  const int bk = blockIdx.x;
  const int c = cnt[bk];
  const int sx = pstartX[bk];

  if (threadIdx.x < 64) lcnt[threadIdx.x] = 0;
  __syncthreads();
  for (int j = threadIdx.x; j < c; j += 256)
    atomicAdd(&lcnt[(staged[sx + j].x >> 16) & 63u], 1);
  __syncthreads();
  if (threadIdx.x == 0) {
    int a = 0;
    for (int i = 0; i < 64; ++i) { lstart[i] = a; lcur[i] = a; a += lcnt[i]; }
  }
  __syncthreads();
  if (threadIdx.x < 64) {
    const int gr = bk * 64 + threadIdx.x;
    if (gr < n) row_start[gr] = sx + lstart[threadIdx.x];
  }
  if (c <= RCAP) {
    for (int j = threadIdx.x; j < c; j += 256) {
      const uint2 p = staged[sx + j];
      const unsigned rl = (p.x >> 16) & 63u;
      const int pos = atomicAdd(&lcur[rl], 1);
      lbuf[pos] = pack_ep(p);
    }
    __syncthreads();
    for (int j = threadIdx.x; j < c; j += 256) ep[sx + j] = lbuf[j];
  } else {  // pathological skew fallback
    for (int j = threadIdx.x; j < c; j += 256) {
      const uint2 p = staged[sx + j];
      const unsigned rl = (p.x >> 16) & 63u;
      const int pos = atomicAdd(&lcur[rl], 1);
      ep[sx + pos] = pack_ep(p);
    }
  }
}

// ---------------- gather: wave per row, paired edges ----------------
__global__ __launch_bounds__(256) void gather_kernel(
    const int* __restrict__ row_start, const unsigned* __restrict__ ep,
    const ushort* __restrict__ Y, const float* __restrict__ bias,
    float* __restrict__ out, int n)
{
  const int wid = (int)((blockIdx.x * 256u + threadIdx.x) >> 6);
  if (wid >= n) return;
  const int lane = threadIdx.x & 63;
  const int half = lane >> 5;          // which edge of the pair
  const int l32 = lane & 31;           // feature quad: l32*4 .. +3
  const int js = row_start[wid];
  const int je = row_start[wid + 1];
  float a0 = 0.f, a1 = 0.f, a2 = 0.f, a3 = 0.f;

  auto acc1 = [&](unsigned p) {
    const size_t yoff = (size_t)(p & 0x3FFFFu) * 128u + l32 * 4;
    const ushort4 h = *(const ushort4*)(Y + yoff);
    const float v = (float)(p >> 18) * (1.f / 16383.f);
    a0 = fmaf(v, bf2f(h.x), a0);
    a1 = fmaf(v, bf2f(h.y), a1);
    a2 = fmaf(v, bf2f(h.z), a2);
    a3 = fmaf(v, bf2f(h.w), a3);
  };

  int j = js;
  for (; j + 7 < je; j += 8) {         // 4 pairs = 8 edges per iter
    const unsigned p0 = ep[j + half];
    const unsigned p1 = ep[j + 2 + half];
    const unsigned p2 = ep[j + 4 + half];
    const unsigned p3 = ep[j + 6 + half];
    acc1(p0); acc1(p1); acc1(p2); acc1(p3);
  }
  for (; j + 1 < je; j += 2) acc1(ep[j + half]);
  if (j < je && half == 0) acc1(ep[j]);   // odd tail: lower half only

  // combine the two halves (features are the same quad in both)
  a0 += __shfl_xor(a0, 32);
  a1 += __shfl_xor(a1, 32);
  a2 += __shfl_xor(a2, 32);
  a3 += __shfl_xor(a3, 32);
  if (half == 0) {
    const float4 bb = ((const float4*)bias)[l32];
    *(float4*)(out + (size_t)wid * 128 + l32 * 4) =
        make_float4(a0 + bb.x, a1 + bb.y, a2 + bb.z, a3 + bb.w);
  }
}

// ---------------- fallback (atomic path, fp32 vector gemm) ----------------
template <typename YT>
__global__ __launch_bounds__(256, 2) void gemm_kernel(
    const float* __restrict__ X, const float* __restrict__ W,
    YT* __restrict__ Y, int n_rows, int col0, int ystride)
{
  __shared__ float Xs[64][128];
  __shared__ float Ws[128][64];
  const int tid = threadIdx.x;
  const int row0 = blockIdx.y * 64;
  {
    const int lane = tid & 31;
    const int r = tid >> 5;
#pragma unroll
    for (int i = 0; i < 8; ++i) {
      const int rr = r + i * 8;
      const int gr = row0 + rr;
      float4 v = make_float4(0.f, 0.f, 0.f, 0.f);
      if (gr < n_rows) v = ((const float4*)(X + (size_t)gr * 128))[lane];
      ((float4*)&Xs[rr][0])[lane ^ ((rr >> 2) & 7)] = v;
    }
  }
  {
    const int gc0 = col0 + blockIdx.x * 64;
    const int b = gc0 >> 7;
    const int cc0 = gc0 & 127;
    const float* Wb = W + (size_t)b * 128 * 128 + cc0;
    const int lane16 = tid & 15;
    const int f = tid >> 4;
#pragma unroll
    for (int i = 0; i < 8; ++i) {
      const int ff = f + i * 16;
      const float4 v = *(const float4*)(Wb + (size_t)ff * 128 + lane16 * 4);
      ((float4*)&Ws[ff][0])[lane16] = v;
    }
  }
  __syncthreads();
  const int tx = tid & 15;
  const int ty = tid >> 4;
  float acc[4][4] = {};
#pragma unroll 2
  for (int f0 = 0; f0 < 128; f0 += 4) {
    float4 a[4];
#pragma unroll
    for (int i = 0; i < 4; ++i) {
      const int r = ty * 4 + i;
      a[i] = ((const float4*)&Xs[r][0])[(f0 >> 2) ^ ((r >> 2) & 7)];
    }
#pragma unroll
    for (int k = 0; k < 4; ++k) {
      const float4 b = *(const float4*)&Ws[f0 + k][tx * 4];
#pragma unroll
      for (int i = 0; i < 4; ++i) {
        const float av = (&a[i].x)[k];
        acc[i][0] = fmaf(av, b.x, acc[i][0]);
        acc[i][1] = fmaf(av, b.y, acc[i][1]);
        acc[i][2] = fmaf(av, b.z, acc[i][2]);
        acc[i][3] = fmaf(av, b.w, acc[i][3]);
      }
    }
  }
  const int yc = blockIdx.x * 64 + tx * 4;
#pragma unroll
  for (int i = 0; i < 4; ++i) {
    const int gr = row0 + ty * 4 + i;
    if (gr >= n_rows) continue;
    *(float4*)(Y + (size_t)gr * ystride + yc) =
        make_float4(acc[i][0], acc[i][1], acc[i][2], acc[i][3]);
  }
}

__global__ __launch_bounds__(256) void init_out_kernel(
    float* __restrict__ out, const float* __restrict__ bias, int nquads)
{
  int i = blockIdx.x * blockDim.x + threadIdx.x;
  if (i >= nquads) return;
  const float4 b = ((const float4*)bias)[i & 31];
  ((float4*)out)[i] = b;
}

__global__ __launch_bounds__(256) void scatter_kernel(
    const int* __restrict__ rows, const int* __restrict__ cols,
    const float* __restrict__ vals, const float* __restrict__ Y,
    int ystride, int yblk, unsigned epb, unsigned ntot,
    float* __restrict__ out)
{
  const unsigned e = blockIdx.x * 8u + (threadIdx.x >> 5);
  if (e >= ntot) return;
  const int lane = threadIdx.x & 31;
  const int row = rows[e];
  const int col = cols[e];
  const float v = vals[e];
  const unsigned b = e / epb;
  const float4 y = *(const float4*)(Y + (size_t)col * ystride + (size_t)b * yblk + lane * 4);
  float* o = out + (size_t)row * 128 + lane * 4;
  atomicAdd(o + 0, v * y.x);
  atomicAdd(o + 1, v * y.y);
  atomicAdd(o + 2, v * y.z);
  atomicAdd(o + 3, v * y.w);
}

extern "C" void kernel_launch(void* const* d_in, const int* in_sizes, int n_in,
                              void* d_out, int out_size, void* d_ws, size_t ws_size,
                              hipStream_t stream) {
  const float* X    = (const float*)d_in[0];
  const int*   rows = (const int*)d_in[1];
  const int*   cols = (const int*)d_in[2];
  const float* vals = (const float*)d_in[3];
  const float* W    = (const float*)d_in[4];
  const float* bias = (const float*)d_in[5];
  float* out = (float*)d_out;

  const int n = out_size / 128;                 // 50000
  const unsigned ntot = (unsigned)in_sizes[1];  // 3.2M flat
  const unsigned epb = ntot / 4u;
  const int nbuk = (n + 63) >> 6;               // 782

  auto align = [](size_t x) { return (x + 255) & ~(size_t)255; };
  const size_t sz_cnt    = align((size_t)nbuk * 4);
  const size_t sz_px     = align((size_t)nbuk * 4);
  const size_t sz_rstart = align((size_t)(n + 1) * 4);
  const size_t sz_cnt2   = align((size_t)NBLK * nbuk * 4);
  const size_t sz_bst2   = align((size_t)NBLK * nbuk * 4);
  const size_t sz_staged = align((size_t)ntot * 8 + 256);
  const size_t sz_ep     = align((size_t)ntot * 4);
  const size_t sz_y      = align((size_t)n * 512 * 2);
  const size_t sz_xb     = align((size_t)n * 128 * 2);
  const size_t sz_wt     = align((size_t)512 * 128 * 2);
  const size_t meta = sz_cnt + sz_px + sz_rstart + sz_cnt2 + sz_bst2 + sz_staged + sz_ep;

  char* ws = (char*)d_ws;
  int*      cnt       = (int*)(ws);
  int*      pstartX   = (int*)(ws + sz_cnt);
  int*      row_start = (int*)(ws + sz_cnt + sz_px);
  int*      cnt2      = (int*)(ws + sz_cnt + sz_px + sz_rstart);
  int*      bstart2   = (int*)(ws + sz_cnt + sz_px + sz_rstart + sz_cnt2);
  uint2*    staged    = (uint2*)(ws + sz_cnt + sz_px + sz_rstart + sz_cnt2 + sz_bst2);
  unsigned* ep        = (unsigned*)(ws + meta - sz_ep);
  ushort*   Y         = (ushort*)(ws + meta);
  ushort*   Xb        = (ushort*)(ws + meta + sz_y);
  ushort*   Wt        = (ushort*)(ws + meta + sz_y + sz_xb);

  const bool fast_ok = (n <= 65536) && (nbuk <= NBUK_MAX) && (nbuk <= 1024) &&
                       (ntot % 4u == 0u) && (in_sizes[0] == n * 128) &&
                       (in_sizes[4] == 512 * 128) &&
                       (ws_size >= meta + sz_y + sz_xb + sz_wt);

  if (fast_ok) {
    const unsigned chunk = (((ntot + NBLK - 1u) / NBLK) + 7u) & ~7u;
    hipMemsetAsync(cnt, 0, (size_t)nbuk * 4, stream);
    hist2_kernel<<<dim3(NBLK), dim3(256), 0, stream>>>(
        rows, cnt, cnt2, ntot, nbuk, chunk);
    scan2_kernel<<<dim3(1), dim3(1024), 0, stream>>>(
        cnt, pstartX, row_start, nbuk, n, ntot);
    scanB_kernel<<<dim3((nbuk + 3) / 4), dim3(256), 0, stream>>>(
        cnt2, pstartX, bstart2, nbuk);
    bscatter2_kernel<<<dim3(NBLK), dim3(256), 0, stream>>>(
        rows, cols, vals, bstart2, staged, ntot, epb, nbuk, chunk);
    reorder_kernel<<<dim3(nbuk), dim3(256), 0, stream>>>(
        cnt, pstartX, staged, ep, row_start, n);
    const int nx8 = n * 16;
    prep_kernel<<<dim3((nx8 + 8192 + 255) / 256), dim3(256), 0, stream>>>(
        X, W, Xb, Wt, nx8);
    mfma_gemm_kernel<<<dim3(8, (n + 63) / 64), dim3(256), 0, stream>>>(
        Xb, Wt, Y, n);
    const unsigned gblk = (unsigned)((n + 3) / 4);
    gather_kernel<<<dim3(gblk), dim3(256), 0, stream>>>(
        row_start, ep, Y, bias, out, n);
    return;
  }

  // Fallback: atomic path (fp32 vector gemm)
  {
    const int nquads = n * 32;
    init_out_kernel<<<dim3((nquads + 255) / 256), dim3(256), 0, stream>>>(out, bias, nquads);
    float* Yf = (float*)d_ws;
    const size_t need_fused = (size_t)n * 512 * sizeof(float);
    if (ws_size >= need_fused) {
      dim3 g(512 / 64, (n + 63) / 64);
      gemm_kernel<float><<<g, dim3(256), 0, stream>>>(X, W, Yf, n, 0, 512);
      const unsigned nblk = (ntot + 7) / 8;
      scatter_kernel<<<dim3(nblk), dim3(256), 0, stream>>>(
          rows, cols, vals, Yf, 512, 128, epb, ntot, out);
    } else {
      for (unsigned b = 0; b < 4; ++b) {
        dim3 g(128 / 64, (n + 63) / 64);
        gemm_kernel<float><<<g, dim3(256), 0, stream>>>(X, W, Yf, n, (int)(b * 128), 128);
        const unsigned nblk = (epb + 7) / 8;
        scatter_kernel<<<dim3(nblk), dim3(256), 0, stream>>>(
            rows + (size_t)b * epb, cols + (size_t)b * epb, vals + (size_t)b * epb,
            Yf, 128, 0, epb, epb, out);
      }
    }
  }
}

// Round 11
// 238.095 us; speedup vs baseline: 3.1494x; 1.0460x over previous
//
#include <hip/hip_runtime.h>
#include <hip/hip_bf16.h>
#include <type_traits>

// out = sum_b A_b @ (X @ W_b) + bias
// 1) histprep : blocks[0,NBLK) bucket histogram; blocks[NBLK,..) X/W -> bf16 prep
// 2) scan2    : exclusive scan of exact counts -> pstartX; row_start[n]=ntot
// 3) scanB    : per-bucket exscan over 512 block counts -> bstart2[blk][bk]
// 4) bscatter2: LDS-binned scatter with pure-LDS cursors, zero global atomics
// 5) reordmm  : blocks[0,nbuk) counting sort -> packed 4B ep + row_start;
//               blocks[nbuk,..) MFMA GEMM Y = Xb @ Wt^T  (independent -> overlap)
// 6) gather   : wave per row, QUARTER-wave per edge (16 lanes, 16B Y loads)

#define NBUK_MAX 800
#define RCAP 8192
#define NBLK 512        // blocks for hist/bscatter2; scanB hardcodes 64x8=512

typedef __attribute__((ext_vector_type(8))) short short8;
typedef __attribute__((ext_vector_type(8))) unsigned short ushort8;
typedef __attribute__((ext_vector_type(4))) float f32x4;

static __device__ __forceinline__ ushort f2bf(float f) {
  __hip_bfloat16 h = __float2bfloat16(f);
  return *(ushort*)&h;
}
static __device__ __forceinline__ float bf2f(ushort u) {
  return __uint_as_float(((unsigned)u) << 16);
}

// ---------------- histprep: hist blocks + prep blocks ----------------
__global__ __launch_bounds__(256) void histprep_kernel(
    const int* __restrict__ rows, int* __restrict__ cnt,
    int* __restrict__ cnt2,
    const float* __restrict__ X, const float* __restrict__ W,
    ushort* __restrict__ Xb, ushort* __restrict__ Wt,
    unsigned ntot, int nbuk, unsigned chunk, int nx8)
{
  __shared__ int lcnt[NBUK_MAX];
  if (blockIdx.x < NBLK) {
    for (int i = threadIdx.x; i < nbuk; i += 256) lcnt[i] = 0;
    __syncthreads();
    const unsigned beg = blockIdx.x * chunk;
    const unsigned end = (beg + chunk < ntot) ? (beg + chunk) : ntot;
    if (beg < end) {
      const unsigned q0 = beg >> 2, q1 = end >> 2;
      for (unsigned i = q0 + threadIdx.x; i < q1; i += 256) {
        const int4 r4 = ((const int4*)rows)[i];
        atomicAdd(&lcnt[((unsigned)r4.x) >> 6], 1);
        atomicAdd(&lcnt[((unsigned)r4.y) >> 6], 1);
        atomicAdd(&lcnt[((unsigned)r4.z) >> 6], 1);
        atomicAdd(&lcnt[((unsigned)r4.w) >> 6], 1);
      }
    }
    __syncthreads();
    int* myrow = cnt2 + (size_t)blockIdx.x * nbuk;
    for (int i = threadIdx.x; i < nbuk; i += 256) {
      const int c = lcnt[i];
      myrow[i] = c;
      if (c) atomicAdd(&cnt[i], c);
    }
  } else {
    const int t = (blockIdx.x - NBLK) * 256 + threadIdx.x;
    if (t < nx8) {
      const float4 v0 = ((const float4*)X)[t * 2];
      const float4 v1 = ((const float4*)X)[t * 2 + 1];
      ushort4 o0, o1;
      o0.x = f2bf(v0.x); o0.y = f2bf(v0.y); o0.z = f2bf(v0.z); o0.w = f2bf(v0.w);
      o1.x = f2bf(v1.x); o1.y = f2bf(v1.y); o1.z = f2bf(v1.z); o1.w = f2bf(v1.w);
      ((ushort4*)Xb)[t * 2] = o0;
      ((ushort4*)Xb)[t * 2 + 1] = o1;
    } else if (t < nx8 + 8192) {
      const int u = t - nx8;
      const int gc = u >> 4;
      const int f0 = (u & 15) * 8;
      const float* src = W + (size_t)((gc >> 7) * 128) * 128 + (gc & 127);
      ushort4 o0, o1;
      o0.x = f2bf(src[(size_t)(f0 + 0) * 128]);
      o0.y = f2bf(src[(size_t)(f0 + 1) * 128]);
      o0.z = f2bf(src[(size_t)(f0 + 2) * 128]);
      o0.w = f2bf(src[(size_t)(f0 + 3) * 128]);
      o1.x = f2bf(src[(size_t)(f0 + 4) * 128]);
      o1.y = f2bf(src[(size_t)(f0 + 5) * 128]);
      o1.z = f2bf(src[(size_t)(f0 + 6) * 128]);
      o1.w = f2bf(src[(size_t)(f0 + 7) * 128]);
      ((ushort4*)(Wt + (size_t)gc * 128 + f0))[0] = o0;
      ((ushort4*)(Wt + (size_t)gc * 128 + f0))[1] = o1;
    }
  }
}

// ---------------- scan2: exact exclusive scan ----------------
__global__ __launch_bounds__(1024) void scan2_kernel(
    const int* __restrict__ cnt, int* __restrict__ pstartX,
    int* __restrict__ row_start, int nbuk, int n, unsigned ntot)
{
  __shared__ int buf[1024];
  const int t = threadIdx.x;
  const int c = (t < nbuk) ? cnt[t] : 0;
  buf[t] = c;
  __syncthreads();
  for (int off = 1; off < 1024; off <<= 1) {
    const int add = (t >= off) ? buf[t - off] : 0;
    __syncthreads();
    buf[t] += add;
    __syncthreads();
  }
  if (t < nbuk) pstartX[t] = buf[t] - c;
  if (t == 0) row_start[n] = (int)ntot;
}

// ---------------- scanB: per-bucket exscan over 512 block counts ----------
__global__ __launch_bounds__(256) void scanB_kernel(
    const int* __restrict__ cnt2, const int* __restrict__ pstartX,
    int* __restrict__ bstart2, int nbuk)
{
  const int bk = blockIdx.x * 4 + (threadIdx.x >> 6);
  if (bk >= nbuk) return;
  const int lane = threadIdx.x & 63;
  int v[8];
  int lanesum = 0;
#pragma unroll
  for (int i = 0; i < 8; ++i) {
    v[i] = cnt2[(size_t)(lane * 8 + i) * nbuk + bk];
    lanesum += v[i];
  }
  int incl = lanesum;
#pragma unroll
  for (int off = 1; off < 64; off <<= 1) {
    const int t = __shfl_up(incl, off);
    if (lane >= off) incl += t;
  }
  int run = pstartX[bk] + (incl - lanesum);
#pragma unroll
  for (int i = 0; i < 8; ++i) {
    bstart2[(size_t)(lane * 8 + i) * nbuk + bk] = run;
    run += v[i];
  }
}

// ---------------- bscatter2: LDS bins, pure-LDS cursors ----------------
// payload: x = row<<16 | col ; y = hop<<30 | val_bits (val in [0,1) => 30 bits)
__global__ __launch_bounds__(256) void bscatter2_kernel(
    const int* __restrict__ rows, const int* __restrict__ cols,
    const float* __restrict__ vals, const int* __restrict__ bstart2,
    uint2* __restrict__ staged, unsigned ntot, unsigned epb, int nbuk,
    unsigned chunk)
{
  __shared__ int bcnt[NBUK_MAX];
  __shared__ int lcur[NBUK_MAX];
  __shared__ uint2 bins[NBUK_MAX * 8];
  {
    const int* myrow = bstart2 + (size_t)blockIdx.x * nbuk;
    for (int i = threadIdx.x; i < nbuk; i += 256) {
      bcnt[i] = 0;
      lcur[i] = myrow[i];
    }
  }
  __syncthreads();

  const unsigned beg = blockIdx.x * chunk;
  const unsigned end = (beg + chunk < ntot) ? (beg + chunk) : ntot;

  auto push = [&](unsigned r, unsigned c, unsigned hop, float v) {
    const uint2 pay = make_uint2((r << 16) | c, (hop << 30) | __float_as_uint(v));
    const int bk = (int)(r >> 6);
    const int p = atomicAdd(&bcnt[bk], 1);
    if (p < 8) bins[bk * 8 + p] = pay;
    else {
      const int gp = atomicAdd(&lcur[bk], 1);
      staged[gp] = pay;
    }
  };

  for (unsigned base = beg; base < end; base += 2048) {
    const unsigned e0 = base + threadIdx.x * 8u;
    if (e0 + 7 < end) {
#pragma unroll
      for (int g = 0; g < 2; ++g) {
        const unsigned eg = e0 + (unsigned)g * 4u;
        const int4 r4 = *(const int4*)(rows + eg);
        const int4 c4 = *(const int4*)(cols + eg);
        const float4 v4 = *(const float4*)(vals + eg);
#pragma unroll
        for (int q = 0; q < 4; ++q) {
          const unsigned e = eg + q;
          const unsigned hop = (e >= 2u * epb) ? ((e >= 3u * epb) ? 3u : 2u)
                                               : ((e >= epb) ? 1u : 0u);
          push((unsigned)((&r4.x)[q]), (unsigned)((&c4.x)[q]), hop, (&v4.x)[q]);
        }
      }
    } else {
      for (unsigned e = e0; e < end && e < e0 + 8; ++e) {
        const unsigned hop = (e >= 2u * epb) ? ((e >= 3u * epb) ? 3u : 2u)
                                             : ((e >= epb) ? 1u : 0u);
        push((unsigned)rows[e], (unsigned)cols[e], hop, vals[e]);
      }
    }
    __syncthreads();
    for (int bk = threadIdx.x; bk < nbuk; bk += 256) {
      if (bcnt[bk] >= 8) {
        const int gp = lcur[bk];
        uint2* dst = staged + gp;
#pragma unroll
        for (int q = 0; q < 8; ++q) dst[q] = bins[bk * 8 + q];
        lcur[bk] = gp + 8;
        bcnt[bk] = 0;
      }
    }
    __syncthreads();
  }
  for (int bk = threadIdx.x; bk < nbuk; bk += 256) {
    const int c = bcnt[bk];
    if (c > 0) {
      const int gp = lcur[bk];
      for (int q = 0; q < c; ++q) staged[gp + q] = bins[bk * 8 + q];
    }
  }
}

// ---------------- reordmm: reorder blocks + mfma blocks ----------------
// ep word = (val_q14 << 18) | (col*4 + hop);  yoff = (word & 0x3FFFF) * 128
static __device__ __forceinline__ unsigned pack_ep(uint2 p) {
  const unsigned col = p.x & 0xFFFFu;
  const unsigned hop = p.y >> 30;
  const float v = __uint_as_float(p.y & 0x3FFFFFFFu);
  const unsigned vq = (unsigned)(v * 16383.f + 0.5f);
  return (vq << 18) | (col * 4u + hop);
}

__global__ __launch_bounds__(256) void reordmm_kernel(
    const int* __restrict__ cnt, const int* __restrict__ pstartX,
    const uint2* __restrict__ staged, unsigned* __restrict__ ep,
    int* __restrict__ row_start,
    const ushort* __restrict__ Xb, const ushort* __restrict__ Wt,
    ushort* __restrict__ Y, int n, int nbuk)
{
  __shared__ int lcnt[64], lstart[64], lcur[64];
  __shared__ unsigned lbuf[RCAP];

  if (blockIdx.x < (unsigned)nbuk) {
    // ---- reorder role ----
    const int bk = blockIdx.x;
    const int c = cnt[bk];
    const int sx = pstartX[bk];

    if (threadIdx.x < 64) lcnt[threadIdx.x] = 0;
    __syncthreads();
    for (int j = threadIdx.x; j < c; j += 256)
      atomicAdd(&lcnt[(staged[sx + j].x >> 16) & 63u], 1);
    __syncthreads();
    if (threadIdx.x == 0) {
      int a = 0;
      for (int i = 0; i < 64; ++i) { lstart[i] = a; lcur[i] = a; a += lcnt[i]; }
    }
    __syncthreads();
    if (threadIdx.x < 64) {
      const int gr = bk * 64 + threadIdx.x;
      if (gr < n) row_start[gr] = sx + lstart[threadIdx.x];
    }
    if (c <= RCAP) {
      for (int j = threadIdx.x; j < c; j += 256) {
        const uint2 p = staged[sx + j];
        const unsigned rl = (p.x >> 16) & 63u;
        const int pos = atomicAdd(&lcur[rl], 1);
        lbuf[pos] = pack_ep(p);
      }
      __syncthreads();
      for (int j = threadIdx.x; j < c; j += 256) ep[sx + j] = lbuf[j];
    } else {
      for (int j = threadIdx.x; j < c; j += 256) {
        const uint2 p = staged[sx + j];
        const unsigned rl = (p.x >> 16) & 63u;
        const int pos = atomicAdd(&lcur[rl], 1);
        ep[sx + pos] = pack_ep(p);
      }
    }
  } else {
    // ---- mfma role ----
    const int u = (int)blockIdx.x - nbuk;
    const int bx = u & 7;
    const int by = u >> 3;
    const int w = threadIdx.x >> 6;
    const int l = threadIdx.x & 63;
    const int r16 = l & 15;
    const int kg = l >> 4;
    const int row0 = by * 64 + w * 16;
    const int c0 = bx * 64;

    const int gra = min(row0 + r16, n - 1);
    const ushort* ap = Xb + (size_t)gra * 128 + kg * 8;
    const ushort* bp = Wt + (size_t)(c0 + r16) * 128 + kg * 8;

    f32x4 acc[4] = {};
#pragma unroll
    for (int k0 = 0; k0 < 128; k0 += 32) {
      const short8 a = *(const short8*)(ap + k0);
#pragma unroll
      for (int ct = 0; ct < 4; ++ct) {
        const short8 b = *(const short8*)(bp + (size_t)ct * 16 * 128 + k0);
        acc[ct] = __builtin_amdgcn_mfma_f32_16x16x32_bf16(a, b, acc[ct], 0, 0, 0);
      }
    }
    const int rs0 = row0 + kg * 4;
#pragma unroll
    for (int ct = 0; ct < 4; ++ct) {
      const int col = c0 + ct * 16 + r16;
#pragma unroll
      for (int r = 0; r < 4; ++r) {
        const int rs = rs0 + r;
        if (rs < n) Y[(size_t)rs * 512 + col] = f2bf(acc[ct][r]);
      }
    }
  }
}

// ---------------- gather: wave per row, quarter-wave per edge ----------------
__global__ __launch_bounds__(256) void gather_kernel(
    const int* __restrict__ row_start, const unsigned* __restrict__ ep,
    const ushort* __restrict__ Y, const float* __restrict__ bias,
    float* __restrict__ out, int n)
{
  const int wid = (int)((blockIdx.x * 256u + threadIdx.x) >> 6);
  if (wid >= n) return;
  const int lane = threadIdx.x & 63;
  const int qw = lane >> 4;            // which edge of the quad
  const int l16 = lane & 15;           // feature octet: l16*8 .. +7
  const int js = row_start[wid];
  const int je = row_start[wid + 1];
  float a[8];
#pragma unroll
  for (int k = 0; k < 8; ++k) a[k] = 0.f;

  auto acc1 = [&](unsigned p) {
    const ushort8 h = *(const ushort8*)(Y + (size_t)(p & 0x3FFFFu) * 128u + l16 * 8);
    const float v = (float)(p >> 18) * (1.f / 16383.f);
#pragma unroll
    for (int k = 0; k < 8; ++k) a[k] = fmaf(v, bf2f(h[k]), a[k]);
  };

  int j = js;
  for (; j + 15 < je; j += 16) {       // 4 quads = 16 edges per iter
    const unsigned p0 = ep[j + qw];
    const unsigned p1 = ep[j + 4 + qw];
    const unsigned p2 = ep[j + 8 + qw];
    const unsigned p3 = ep[j + 12 + qw];
    acc1(p0); acc1(p1); acc1(p2); acc1(p3);
  }
  for (; j + 3 < je; j += 4) acc1(ep[j + qw]);
  const int rem = je - j;
  if (qw < rem) acc1(ep[j + qw]);      // tail: 1..3 edges

  // combine the 4 quarter-wave partial sums (same feature octet in each)
#pragma unroll
  for (int k = 0; k < 8; ++k) {
    a[k] += __shfl_xor(a[k], 16);
    a[k] += __shfl_xor(a[k], 32);
  }
  if (qw == 0) {
    const float4 b0 = ((const float4*)bias)[l16 * 2];
    const float4 b1 = ((const float4*)bias)[l16 * 2 + 1];
    float* o = out + (size_t)wid * 128 + l16 * 8;
    *(float4*)(o)     = make_float4(a[0] + b0.x, a[1] + b0.y, a[2] + b0.z, a[3] + b0.w);
    *(float4*)(o + 4) = make_float4(a[4] + b1.x, a[5] + b1.y, a[6] + b1.z, a[7] + b1.w);
  }
}

// ---------------- fallback (atomic path, fp32 vector gemm) ----------------
template <typename YT>
__global__ __launch_bounds__(256, 2) void gemm_kernel(
    const float* __restrict__ X, const float* __restrict__ W,
    YT* __restrict__ Y, int n_rows, int col0, int ystride)
{
  __shared__ float Xs[64][128];
  __shared__ float Ws[128][64];
  const int tid = threadIdx.x;
  const int row0 = blockIdx.y * 64;
  {
    const int lane = tid & 31;
    const int r = tid >> 5;
#pragma unroll
    for (int i = 0; i < 8; ++i) {
      const int rr = r + i * 8;
      const int gr = row0 + rr;
      float4 v = make_float4(0.f, 0.f, 0.f, 0.f);
      if (gr < n_rows) v = ((const float4*)(X + (size_t)gr * 128))[lane];
      ((float4*)&Xs[rr][0])[lane ^ ((rr >> 2) & 7)] = v;
    }
  }
  {
    const int gc0 = col0 + blockIdx.x * 64;
    const int b = gc0 >> 7;
    const int cc0 = gc0 & 127;
    const float* Wb = W + (size_t)b * 128 * 128 + cc0;
    const int lane16 = tid & 15;
    const int f = tid >> 4;
#pragma unroll
    for (int i = 0; i < 8; ++i) {
      const int ff = f + i * 16;
      const float4 v = *(const float4*)(Wb + (size_t)ff * 128 + lane16 * 4);
      ((float4*)&Ws[ff][0])[lane16] = v;
    }
  }
  __syncthreads();
  const int tx = tid & 15;
  const int ty = tid >> 4;
  float acc[4][4] = {};
#pragma unroll 2
  for (int f0 = 0; f0 < 128; f0 += 4) {
    float4 a[4];
#pragma unroll
    for (int i = 0; i < 4; ++i) {
      const int r = ty * 4 + i;
      a[i] = ((const float4*)&Xs[r][0])[(f0 >> 2) ^ ((r >> 2) & 7)];
    }
#pragma unroll
    for (int k = 0; k < 4; ++k) {
      const float4 b = *(const float4*)&Ws[f0 + k][tx * 4];
#pragma unroll
      for (int i = 0; i < 4; ++i) {
        const float av = (&a[i].x)[k];
        acc[i][0] = fmaf(av, b.x, acc[i][0]);
        acc[i][1] = fmaf(av, b.y, acc[i][1]);
        acc[i][2] = fmaf(av, b.z, acc[i][2]);
        acc[i][3] = fmaf(av, b.w, acc[i][3]);
      }
    }
  }
  const int yc = blockIdx.x * 64 + tx * 4;
#pragma unroll
  for (int i = 0; i < 4; ++i) {
    const int gr = row0 + ty * 4 + i;
    if (gr >= n_rows) continue;
    *(float4*)(Y + (size_t)gr * ystride + yc) =
        make_float4(acc[i][0], acc[i][1], acc[i][2], acc[i][3]);
  }
}

__global__ __launch_bounds__(256) void init_out_kernel(
    float* __restrict__ out, const float* __restrict__ bias, int nquads)
{
  int i = blockIdx.x * blockDim.x + threadIdx.x;
  if (i >= nquads) return;
  const float4 b = ((const float4*)bias)[i & 31];
  ((float4*)out)[i] = b;
}

__global__ __launch_bounds__(256) void scatter_kernel(
    const int* __restrict__ rows, const int* __restrict__ cols,
    const float* __restrict__ vals, const float* __restrict__ Y,
    int ystride, int yblk, unsigned epb, unsigned ntot,
    float* __restrict__ out)
{
  const unsigned e = blockIdx.x * 8u + (threadIdx.x >> 5);
  if (e >= ntot) return;
  const int lane = threadIdx.x & 31;
  const int row = rows[e];
  const int col = cols[e];
  const float v = vals[e];
  const unsigned b = e / epb;
  const float4 y = *(const float4*)(Y + (size_t)col * ystride + (size_t)b * yblk + lane * 4);
  float* o = out + (size_t)row * 128 + lane * 4;
  atomicAdd(o + 0, v * y.x);
  atomicAdd(o + 1, v * y.y);
  atomicAdd(o + 2, v * y.z);
  atomicAdd(o + 3, v * y.w);
}

extern "C" void kernel_launch(void* const* d_in, const int* in_sizes, int n_in,
                              void* d_out, int out_size, void* d_ws, size_t ws_size,
                              hipStream_t stream) {
  const float* X    = (const float*)d_in[0];
  const int*   rows = (const int*)d_in[1];
  const int*   cols = (const int*)d_in[2];
  const float* vals = (const float*)d_in[3];
  const float* W    = (const float*)d_in[4];
  const float* bias = (const float*)d_in[5];
  float* out = (float*)d_out;

  const int n = out_size / 128;                 // 50000
  const unsigned ntot = (unsigned)in_sizes[1];  // 3.2M flat
  const unsigned epb = ntot / 4u;
  const int nbuk = (n + 63) >> 6;               // 782

  auto align = [](size_t x) { return (x + 255) & ~(size_t)255; };
  const size_t sz_cnt    = align((size_t)nbuk * 4);
  const size_t sz_px     = align((size_t)nbuk * 4);
  const size_t sz_rstart = align((size_t)(n + 1) * 4);
  const size_t sz_cnt2   = align((size_t)NBLK * nbuk * 4);
  const size_t sz_bst2   = align((size_t)NBLK * nbuk * 4);
  const size_t sz_staged = align((size_t)ntot * 8 + 256);
  const size_t sz_ep     = align((size_t)ntot * 4);
  const size_t sz_y      = align((size_t)n * 512 * 2);
  const size_t sz_xb     = align((size_t)n * 128 * 2);
  const size_t sz_wt     = align((size_t)512 * 128 * 2);
  const size_t meta = sz_cnt + sz_px + sz_rstart + sz_cnt2 + sz_bst2 + sz_staged + sz_ep;

  char* ws = (char*)d_ws;
  int*      cnt       = (int*)(ws);
  int*      pstartX   = (int*)(ws + sz_cnt);
  int*      row_start = (int*)(ws + sz_cnt + sz_px);
  int*      cnt2      = (int*)(ws + sz_cnt + sz_px + sz_rstart);
  int*      bstart2   = (int*)(ws + sz_cnt + sz_px + sz_rstart + sz_cnt2);
  uint2*    staged    = (uint2*)(ws + sz_cnt + sz_px + sz_rstart + sz_cnt2 + sz_bst2);
  unsigned* ep        = (unsigned*)(ws + meta - sz_ep);
  ushort*   Y         = (ushort*)(ws + meta);
  ushort*   Xb        = (ushort*)(ws + meta + sz_y);
  ushort*   Wt        = (ushort*)(ws + meta + sz_y + sz_xb);

  const bool fast_ok = (n <= 65536) && (nbuk <= NBUK_MAX) && (nbuk <= 1024) &&
                       (ntot % 4u == 0u) && (in_sizes[0] == n * 128) &&
                       (in_sizes[4] == 512 * 128) &&
                       (ws_size >= meta + sz_y + sz_xb + sz_wt);

  if (fast_ok) {
    const unsigned chunk = (((ntot + NBLK - 1u) / NBLK) + 7u) & ~7u;
    const int nx8 = n * 16;
    const int nprep = (nx8 + 8192 + 255) / 256;
    hipMemsetAsync(cnt, 0, (size_t)nbuk * 4, stream);
    histprep_kernel<<<dim3(NBLK + nprep), dim3(256), 0, stream>>>(
        rows, cnt, cnt2, X, W, Xb, Wt, ntot, nbuk, chunk, nx8);
    scan2_kernel<<<dim3(1), dim3(1024), 0, stream>>>(
        cnt, pstartX, row_start, nbuk, n, ntot);
    scanB_kernel<<<dim3((nbuk + 3) / 4), dim3(256), 0, stream>>>(
        cnt2, pstartX, bstart2, nbuk);
    bscatter2_kernel<<<dim3(NBLK), dim3(256), 0, stream>>>(
        rows, cols, vals, bstart2, staged, ntot, epb, nbuk, chunk);
    const int nby = (n + 63) / 64;
    reordmm_kernel<<<dim3(nbuk + 8 * nby), dim3(256), 0, stream>>>(
        cnt, pstartX, staged, ep, row_start, Xb, Wt, Y, n, nbuk);
    const unsigned gblk = (unsigned)((n + 3) / 4);
    gather_kernel<<<dim3(gblk), dim3(256), 0, stream>>>(
        row_start, ep, Y, bias, out, n);
    return;
  }

  // Fallback: atomic path (fp32 vector gemm)
  {
    const int nquads = n * 32;
    init_out_kernel<<<dim3((nquads + 255) / 256), dim3(256), 0, stream>>>(out, bias, nquads);
    float* Yf = (float*)d_ws;
    const size_t need_fused = (size_t)n * 512 * sizeof(float);
    if (ws_size >= need_fused) {
      dim3 g(512 / 64, (n + 63) / 64);
      gemm_kernel<float><<<g, dim3(256), 0, stream>>>(X, W, Yf, n, 0, 512);
      const unsigned nblk = (ntot + 7) / 8;
      scatter_kernel<<<dim3(nblk), dim3(256), 0, stream>>>(
          rows, cols, vals, Yf, 512, 128, epb, ntot, out);
    } else {
      for (unsigned b = 0; b < 4; ++b) {
        dim3 g(128 / 64, (n + 63) / 64);
        gemm_kernel<float><<<g, dim3(256), 0, stream>>>(X, W, Yf, n, (int)(b * 128), 128);
        const unsigned nblk = (epb + 7) / 8;
        scatter_kernel<<<dim3(nblk), dim3(256), 0, stream>>>(
            rows + (size_t)b * epb, cols + (size_t)b * epb, vals + (size_t)b * epb,
            Yf, 128, 0, epb, epb, out);
      }
    }
  }
}

// Round 12
// 237.331 us; speedup vs baseline: 3.1595x; 1.0032x over previous
//
#include <hip/hip_runtime.h>
#include <hip/hip_bf16.h>
#include <type_traits>

// out = sum_b A_b @ (X @ W_b) + bias
// 1) histprep : blocks[0,NBLK) bucket histogram; blocks[NBLK,..) X/W -> bf16 prep
// 2) scanB2   : wave per bucket: global bucket prefix (from cnt) + per-block
//               exscan over 512 block counts -> bstart2, pstartX, row_start[n]
// 3) bscatter2: LDS-binned scatter with pure-LDS cursors, zero global atomics
// 4) reordmm  : blocks[0,nbuk) counting sort -> packed 4B ep + row_start;
//               blocks[nbuk,..) MFMA GEMM Y = Xb @ Wt^T  (independent -> overlap)
// 5) gather   : wave per row, quarter-wave per edge (16 lanes, 16B Y loads), 32-deep

#define NBUK_MAX 800
#define RCAP 8192
#define NBLK 512        // blocks for hist/bscatter2; scanB2 hardcodes 64x8=512

typedef __attribute__((ext_vector_type(8))) short short8;
typedef __attribute__((ext_vector_type(8))) unsigned short ushort8;
typedef __attribute__((ext_vector_type(4))) float f32x4;

static __device__ __forceinline__ ushort f2bf(float f) {
  __hip_bfloat16 h = __float2bfloat16(f);
  return *(ushort*)&h;
}
static __device__ __forceinline__ float bf2f(ushort u) {
  return __uint_as_float(((unsigned)u) << 16);
}

// ---------------- histprep: hist blocks + prep blocks ----------------
__global__ __launch_bounds__(256) void histprep_kernel(
    const int* __restrict__ rows, int* __restrict__ cnt,
    int* __restrict__ cnt2,
    const float* __restrict__ X, const float* __restrict__ W,
    ushort* __restrict__ Xb, ushort* __restrict__ Wt,
    unsigned ntot, int nbuk, unsigned chunk, int nx8)
{
  __shared__ int lcnt[NBUK_MAX];
  if (blockIdx.x < NBLK) {
    for (int i = threadIdx.x; i < nbuk; i += 256) lcnt[i] = 0;
    __syncthreads();
    const unsigned beg = blockIdx.x * chunk;
    const unsigned end = (beg + chunk < ntot) ? (beg + chunk) : ntot;
    if (beg < end) {
      const unsigned q0 = beg >> 2, q1 = end >> 2;
      for (unsigned i = q0 + threadIdx.x; i < q1; i += 256) {
        const int4 r4 = ((const int4*)rows)[i];
        atomicAdd(&lcnt[((unsigned)r4.x) >> 6], 1);
        atomicAdd(&lcnt[((unsigned)r4.y) >> 6], 1);
        atomicAdd(&lcnt[((unsigned)r4.z) >> 6], 1);
        atomicAdd(&lcnt[((unsigned)r4.w) >> 6], 1);
      }
    }
    __syncthreads();
    int* myrow = cnt2 + (size_t)blockIdx.x * nbuk;
    for (int i = threadIdx.x; i < nbuk; i += 256) {
      const int c = lcnt[i];
      myrow[i] = c;
      if (c) atomicAdd(&cnt[i], c);
    }
  } else {
    const int t = (blockIdx.x - NBLK) * 256 + threadIdx.x;
    if (t < nx8) {
      const float4 v0 = ((const float4*)X)[t * 2];
      const float4 v1 = ((const float4*)X)[t * 2 + 1];
      ushort4 o0, o1;
      o0.x = f2bf(v0.x); o0.y = f2bf(v0.y); o0.z = f2bf(v0.z); o0.w = f2bf(v0.w);
      o1.x = f2bf(v1.x); o1.y = f2bf(v1.y); o1.z = f2bf(v1.z); o1.w = f2bf(v1.w);
      ((ushort4*)Xb)[t * 2] = o0;
      ((ushort4*)Xb)[t * 2 + 1] = o1;
    } else if (t < nx8 + 8192) {
      const int u = t - nx8;
      const int gc = u >> 4;
      const int f0 = (u & 15) * 8;
      const float* src = W + (size_t)((gc >> 7) * 128) * 128 + (gc & 127);
      ushort4 o0, o1;
      o0.x = f2bf(src[(size_t)(f0 + 0) * 128]);
      o0.y = f2bf(src[(size_t)(f0 + 1) * 128]);
      o0.z = f2bf(src[(size_t)(f0 + 2) * 128]);
      o0.w = f2bf(src[(size_t)(f0 + 3) * 128]);
      o1.x = f2bf(src[(size_t)(f0 + 4) * 128]);
      o1.y = f2bf(src[(size_t)(f0 + 5) * 128]);
      o1.z = f2bf(src[(size_t)(f0 + 6) * 128]);
      o1.w = f2bf(src[(size_t)(f0 + 7) * 128]);
      ((ushort4*)(Wt + (size_t)gc * 128 + f0))[0] = o0;
      ((ushort4*)(Wt + (size_t)gc * 128 + f0))[1] = o1;
    }
  }
}

// ---------------- scanB2: self-contained scans (replaces scan2 + scanB) -----
// Wave per bucket: global bucket prefix from cnt (strided sum + butterfly),
// then per-block offsets from cnt2 column (shfl_up exscan over 512 blocks).
__global__ __launch_bounds__(256) void scanB2_kernel(
    const int* __restrict__ cnt, const int* __restrict__ cnt2,
    int* __restrict__ pstartX, int* __restrict__ bstart2,
    int* __restrict__ row_start, int nbuk, int n, unsigned ntot)
{
  __shared__ int lcnt[NBUK_MAX];
  for (int i = threadIdx.x; i < nbuk; i += 256) lcnt[i] = cnt[i];
  __syncthreads();
  if (blockIdx.x == 0 && threadIdx.x == 0) row_start[n] = (int)ntot;

  const int bk = blockIdx.x * 4 + (threadIdx.x >> 6);
  if (bk >= nbuk) return;
  const int lane = threadIdx.x & 63;

  // global exclusive prefix over buckets < bk
  int pre = 0;
  for (int i = lane; i < bk; i += 64) pre += lcnt[i];
#pragma unroll
  for (int off = 32; off; off >>= 1) pre += __shfl_xor(pre, off);

  // per-block exscan over the 512 block counts of this bucket
  int v[8];
  int lanesum = 0;
#pragma unroll
  for (int i = 0; i < 8; ++i) {
    v[i] = cnt2[(size_t)(lane * 8 + i) * nbuk + bk];
    lanesum += v[i];
  }
  int incl = lanesum;
#pragma unroll
  for (int off = 1; off < 64; off <<= 1) {
    const int t = __shfl_up(incl, off);
    if (lane >= off) incl += t;
  }
  int run = pre + (incl - lanesum);
#pragma unroll
  for (int i = 0; i < 8; ++i) {
    bstart2[(size_t)(lane * 8 + i) * nbuk + bk] = run;
    run += v[i];
  }
  if (lane == 0) pstartX[bk] = pre;
}

// ---------------- bscatter2: LDS bins, pure-LDS cursors ----------------
// payload: x = row<<16 | col ; y = hop<<30 | val_bits (val in [0,1) => 30 bits)
__global__ __launch_bounds__(256) void bscatter2_kernel(
    const int* __restrict__ rows, const int* __restrict__ cols,
    const float* __restrict__ vals, const int* __restrict__ bstart2,
    uint2* __restrict__ staged, unsigned ntot, unsigned epb, int nbuk,
    unsigned chunk)
{
  __shared__ int bcnt[NBUK_MAX];
  __shared__ int lcur[NBUK_MAX];
  __shared__ uint2 bins[NBUK_MAX * 8];
  {
    const int* myrow = bstart2 + (size_t)blockIdx.x * nbuk;
    for (int i = threadIdx.x; i < nbuk; i += 256) {
      bcnt[i] = 0;
      lcur[i] = myrow[i];
    }
  }
  __syncthreads();

  const unsigned beg = blockIdx.x * chunk;
  const unsigned end = (beg + chunk < ntot) ? (beg + chunk) : ntot;

  auto push = [&](unsigned r, unsigned c, unsigned hop, float v) {
    const uint2 pay = make_uint2((r << 16) | c, (hop << 30) | __float_as_uint(v));
    const int bk = (int)(r >> 6);
    const int p = atomicAdd(&bcnt[bk], 1);
    if (p < 8) bins[bk * 8 + p] = pay;
    else {
      const int gp = atomicAdd(&lcur[bk], 1);
      staged[gp] = pay;
    }
  };

  for (unsigned base = beg; base < end; base += 2048) {
    const unsigned e0 = base + threadIdx.x * 8u;
    if (e0 + 7 < end) {
#pragma unroll
      for (int g = 0; g < 2; ++g) {
        const unsigned eg = e0 + (unsigned)g * 4u;
        const int4 r4 = *(const int4*)(rows + eg);
        const int4 c4 = *(const int4*)(cols + eg);
        const float4 v4 = *(const float4*)(vals + eg);
#pragma unroll
        for (int q = 0; q < 4; ++q) {
          const unsigned e = eg + q;
          const unsigned hop = (e >= 2u * epb) ? ((e >= 3u * epb) ? 3u : 2u)
                                               : ((e >= epb) ? 1u : 0u);
          push((unsigned)((&r4.x)[q]), (unsigned)((&c4.x)[q]), hop, (&v4.x)[q]);
        }
      }
    } else {
      for (unsigned e = e0; e < end && e < e0 + 8; ++e) {
        const unsigned hop = (e >= 2u * epb) ? ((e >= 3u * epb) ? 3u : 2u)
                                             : ((e >= epb) ? 1u : 0u);
        push((unsigned)rows[e], (unsigned)cols[e], hop, vals[e]);
      }
    }
    __syncthreads();
    for (int bk = threadIdx.x; bk < nbuk; bk += 256) {
      if (bcnt[bk] >= 8) {
        const int gp = lcur[bk];
        uint2* dst = staged + gp;
#pragma unroll
        for (int q = 0; q < 8; ++q) dst[q] = bins[bk * 8 + q];
        lcur[bk] = gp + 8;
        bcnt[bk] = 0;
      }
    }
    __syncthreads();
  }
  for (int bk = threadIdx.x; bk < nbuk; bk += 256) {
    const int c = bcnt[bk];
    if (c > 0) {
      const int gp = lcur[bk];
      for (int q = 0; q < c; ++q) staged[gp + q] = bins[bk * 8 + q];
    }
  }
}

// ---------------- reordmm: reorder blocks + mfma blocks ----------------
// ep word = (val_q14 << 18) | (col*4 + hop);  yoff = (word & 0x3FFFF) * 128
static __device__ __forceinline__ unsigned pack_ep(uint2 p) {
  const unsigned col = p.x & 0xFFFFu;
  const unsigned hop = p.y >> 30;
  const float v = __uint_as_float(p.y & 0x3FFFFFFFu);
  const unsigned vq = (unsigned)(v * 16383.f + 0.5f);
  return (vq << 18) | (col * 4u + hop);
}

__global__ __launch_bounds__(256) void reordmm_kernel(
    const int* __restrict__ cnt, const int* __restrict__ pstartX,
    const uint2* __restrict__ staged, unsigned* __restrict__ ep,
    int* __restrict__ row_start,
    const ushort* __restrict__ Xb, const ushort* __restrict__ Wt,
    ushort* __restrict__ Y, int n, int nbuk)
{
  __shared__ int lcnt[64], lstart[64], lcur[64];
  __shared__ unsigned lbuf[RCAP];

  if (blockIdx.x < (unsigned)nbuk) {
    // ---- reorder role ----
    const int bk = blockIdx.x;
    const int c = cnt[bk];
    const int sx = pstartX[bk];

    if (threadIdx.x < 64) lcnt[threadIdx.x] = 0;
    __syncthreads();
    for (int j = threadIdx.x; j < c; j += 256)
      atomicAdd(&lcnt[(staged[sx + j].x >> 16) & 63u], 1);
    __syncthreads();
    if (threadIdx.x == 0) {
      int a = 0;
      for (int i = 0; i < 64; ++i) { lstart[i] = a; lcur[i] = a; a += lcnt[i]; }
    }
    __syncthreads();
    if (threadIdx.x < 64) {
      const int gr = bk * 64 + threadIdx.x;
      if (gr < n) row_start[gr] = sx + lstart[threadIdx.x];
    }
    if (c <= RCAP) {
      for (int j = threadIdx.x; j < c; j += 256) {
        const uint2 p = staged[sx + j];
        const unsigned rl = (p.x >> 16) & 63u;
        const int pos = atomicAdd(&lcur[rl], 1);
        lbuf[pos] = pack_ep(p);
      }
      __syncthreads();
      for (int j = threadIdx.x; j < c; j += 256) ep[sx + j] = lbuf[j];
    } else {
      for (int j = threadIdx.x; j < c; j += 256) {
        const uint2 p = staged[sx + j];
        const unsigned rl = (p.x >> 16) & 63u;
        const int pos = atomicAdd(&lcur[rl], 1);
        ep[sx + pos] = pack_ep(p);
      }
    }
  } else {
    // ---- mfma role ----
    const int u = (int)blockIdx.x - nbuk;
    const int bx = u & 7;
    const int by = u >> 3;
    const int w = threadIdx.x >> 6;
    const int l = threadIdx.x & 63;
    const int r16 = l & 15;
    const int kg = l >> 4;
    const int row0 = by * 64 + w * 16;
    const int c0 = bx * 64;

    const int gra = min(row0 + r16, n - 1);
    const ushort* ap = Xb + (size_t)gra * 128 + kg * 8;
    const ushort* bp = Wt + (size_t)(c0 + r16) * 128 + kg * 8;

    f32x4 acc[4] = {};
#pragma unroll
    for (int k0 = 0; k0 < 128; k0 += 32) {
      const short8 a = *(const short8*)(ap + k0);
#pragma unroll
      for (int ct = 0; ct < 4; ++ct) {
        const short8 b = *(const short8*)(bp + (size_t)ct * 16 * 128 + k0);
        acc[ct] = __builtin_amdgcn_mfma_f32_16x16x32_bf16(a, b, acc[ct], 0, 0, 0);
      }
    }
    const int rs0 = row0 + kg * 4;
#pragma unroll
    for (int ct = 0; ct < 4; ++ct) {
      const int col = c0 + ct * 16 + r16;
#pragma unroll
      for (int r = 0; r < 4; ++r) {
        const int rs = rs0 + r;
        if (rs < n) Y[(size_t)rs * 512 + col] = f2bf(acc[ct][r]);
      }
    }
  }
}

// ---------------- gather: wave per row, quarter-wave per edge, 32-deep ------
__global__ __launch_bounds__(256) void gather_kernel(
    const int* __restrict__ row_start, const unsigned* __restrict__ ep,
    const ushort* __restrict__ Y, const float* __restrict__ bias,
    float* __restrict__ out, int n)
{
  const int wid = (int)((blockIdx.x * 256u + threadIdx.x) >> 6);
  if (wid >= n) return;
  const int lane = threadIdx.x & 63;
  const int qw = lane >> 4;            // which edge of the quad
  const int l16 = lane & 15;           // feature octet: l16*8 .. +7
  const int js = row_start[wid];
  const int je = row_start[wid + 1];
  float a[8];
#pragma unroll
  for (int k = 0; k < 8; ++k) a[k] = 0.f;

  auto acc1 = [&](unsigned p) {
    const ushort8 h = *(const ushort8*)(Y + (size_t)(p & 0x3FFFFu) * 128u + l16 * 8);
    const float v = (float)(p >> 18) * (1.f / 16383.f);
#pragma unroll
    for (int k = 0; k < 8; ++k) a[k] = fmaf(v, bf2f(h[k]), a[k]);
  };

  int j = js;
  for (; j + 31 < je; j += 32) {       // 8 quads = 32 edges per iter
    const unsigned p0 = ep[j + qw];
    const unsigned p1 = ep[j + 4 + qw];
    const unsigned p2 = ep[j + 8 + qw];
    const unsigned p3 = ep[j + 12 + qw];
    const unsigned p4 = ep[j + 16 + qw];
    const unsigned p5 = ep[j + 20 + qw];
    const unsigned p6 = ep[j + 24 + qw];
    const unsigned p7 = ep[j + 28 + qw];
    acc1(p0); acc1(p1); acc1(p2); acc1(p3);
    acc1(p4); acc1(p5); acc1(p6); acc1(p7);
  }
  for (; j + 3 < je; j += 4) acc1(ep[j + qw]);
  const int rem = je - j;
  if (qw < rem) acc1(ep[j + qw]);      // tail: 1..3 edges

  // combine the 4 quarter-wave partial sums (same feature octet in each)
#pragma unroll
  for (int k = 0; k < 8; ++k) {
    a[k] += __shfl_xor(a[k], 16);
    a[k] += __shfl_xor(a[k], 32);
  }
  if (qw == 0) {
    const float4 b0 = ((const float4*)bias)[l16 * 2];
    const float4 b1 = ((const float4*)bias)[l16 * 2 + 1];
    float* o = out + (size_t)wid * 128 + l16 * 8;
    *(float4*)(o)     = make_float4(a[0] + b0.x, a[1] + b0.y, a[2] + b0.z, a[3] + b0.w);
    *(float4*)(o + 4) = make_float4(a[4] + b1.x, a[5] + b1.y, a[6] + b1.z, a[7] + b1.w);
  }
}

// ---------------- fallback (atomic path, fp32 vector gemm) ----------------
template <typename YT>
__global__ __launch_bounds__(256, 2) void gemm_kernel(
    const float* __restrict__ X, const float* __restrict__ W,
    YT* __restrict__ Y, int n_rows, int col0, int ystride)
{
  __shared__ float Xs[64][128];
  __shared__ float Ws[128][64];
  const int tid = threadIdx.x;
  const int row0 = blockIdx.y * 64;
  {
    const int lane = tid & 31;
    const int r = tid >> 5;
#pragma unroll
    for (int i = 0; i < 8; ++i) {
      const int rr = r + i * 8;
      const int gr = row0 + rr;
      float4 v = make_float4(0.f, 0.f, 0.f, 0.f);
      if (gr < n_rows) v = ((const float4*)(X + (size_t)gr * 128))[lane];
      ((float4*)&Xs[rr][0])[lane ^ ((rr >> 2) & 7)] = v;
    }
  }
  {
    const int gc0 = col0 + blockIdx.x * 64;
    const int b = gc0 >> 7;
    const int cc0 = gc0 & 127;
    const float* Wb = W + (size_t)b * 128 * 128 + cc0;
    const int lane16 = tid & 15;
    const int f = tid >> 4;
#pragma unroll
    for (int i = 0; i < 8; ++i) {
      const int ff = f + i * 16;
      const float4 v = *(const float4*)(Wb + (size_t)ff * 128 + lane16 * 4);
      ((float4*)&Ws[ff][0])[lane16] = v;
    }
  }
  __syncthreads();
  const int tx = tid & 15;
  const int ty = tid >> 4;
  float acc[4][4] = {};
#pragma unroll 2
  for (int f0 = 0; f0 < 128; f0 += 4) {
    float4 a[4];
#pragma unroll
    for (int i = 0; i < 4; ++i) {
      const int r = ty * 4 + i;
      a[i] = ((const float4*)&Xs[r][0])[(f0 >> 2) ^ ((r >> 2) & 7)];
    }
#pragma unroll
    for (int k = 0; k < 4; ++k) {
      const float4 b = *(const float4*)&Ws[f0 + k][tx * 4];
#pragma unroll
      for (int i = 0; i < 4; ++i) {
        const float av = (&a[i].x)[k];
        acc[i][0] = fmaf(av, b.x, acc[i][0]);
        acc[i][1] = fmaf(av, b.y, acc[i][1]);
        acc[i][2] = fmaf(av, b.z, acc[i][2]);
        acc[i][3] = fmaf(av, b.w, acc[i][3]);
      }
    }
  }
  const int yc = blockIdx.x * 64 + tx * 4;
#pragma unroll
  for (int i = 0; i < 4; ++i) {
    const int gr = row0 + ty * 4 + i;
    if (gr >= n_rows) continue;
    *(float4*)(Y + (size_t)gr * ystride + yc) =
        make_float4(acc[i][0], acc[i][1], acc[i][2], acc[i][3]);
  }
}

__global__ __launch_bounds__(256) void init_out_kernel(
    float* __restrict__ out, const float* __restrict__ bias, int nquads)
{
  int i = blockIdx.x * blockDim.x + threadIdx.x;
  if (i >= nquads) return;
  const float4 b = ((const float4*)bias)[i & 31];
  ((float4*)out)[i] = b;
}

__global__ __launch_bounds__(256) void scatter_kernel(
    const int* __restrict__ rows, const int* __restrict__ cols,
    const float* __restrict__ vals, const float* __restrict__ Y,
    int ystride, int yblk, unsigned epb, unsigned ntot,
    float* __restrict__ out)
{
  const unsigned e = blockIdx.x * 8u + (threadIdx.x >> 5);
  if (e >= ntot) return;
  const int lane = threadIdx.x & 31;
  const int row = rows[e];
  const int col = cols[e];
  const float v = vals[e];
  const unsigned b = e / epb;
  const float4 y = *(const float4*)(Y + (size_t)col * ystride + (size_t)b * yblk + lane * 4);
  float* o = out + (size_t)row * 128 + lane * 4;
  atomicAdd(o + 0, v * y.x);
  atomicAdd(o + 1, v * y.y);
  atomicAdd(o + 2, v * y.z);
  atomicAdd(o + 3, v * y.w);
}

extern "C" void kernel_launch(void* const* d_in, const int* in_sizes, int n_in,
                              void* d_out, int out_size, void* d_ws, size_t ws_size,
                              hipStream_t stream) {
  const float* X    = (const float*)d_in[0];
  const int*   rows = (const int*)d_in[1];
  const int*   cols = (const int*)d_in[2];
  const float* vals = (const float*)d_in[3];
  const float* W    = (const float*)d_in[4];
  const float* bias = (const float*)d_in[5];
  float* out = (float*)d_out;

  const int n = out_size / 128;                 // 50000
  const unsigned ntot = (unsigned)in_sizes[1];  // 3.2M flat
  const unsigned epb = ntot / 4u;
  const int nbuk = (n + 63) >> 6;               // 782

  auto align = [](size_t x) { return (x + 255) & ~(size_t)255; };
  const size_t sz_cnt    = align((size_t)nbuk * 4);
  const size_t sz_px     = align((size_t)nbuk * 4);
  const size_t sz_rstart = align((size_t)(n + 1) * 4);
  const size_t sz_cnt2   = align((size_t)NBLK * nbuk * 4);
  const size_t sz_bst2   = align((size_t)NBLK * nbuk * 4);
  const size_t sz_staged = align((size_t)ntot * 8 + 256);
  const size_t sz_ep     = align((size_t)ntot * 4);
  const size_t sz_y      = align((size_t)n * 512 * 2);
  const size_t sz_xb     = align((size_t)n * 128 * 2);
  const size_t sz_wt     = align((size_t)512 * 128 * 2);
  const size_t meta = sz_cnt + sz_px + sz_rstart + sz_cnt2 + sz_bst2 + sz_staged + sz_ep;

  char* ws = (char*)d_ws;
  int*      cnt       = (int*)(ws);
  int*      pstartX   = (int*)(ws + sz_cnt);
  int*      row_start = (int*)(ws + sz_cnt + sz_px);
  int*      cnt2      = (int*)(ws + sz_cnt + sz_px + sz_rstart);
  int*      bstart2   = (int*)(ws + sz_cnt + sz_px + sz_rstart + sz_cnt2);
  uint2*    staged    = (uint2*)(ws + sz_cnt + sz_px + sz_rstart + sz_cnt2 + sz_bst2);
  unsigned* ep        = (unsigned*)(ws + meta - sz_ep);
  ushort*   Y         = (ushort*)(ws + meta);
  ushort*   Xb        = (ushort*)(ws + meta + sz_y);
  ushort*   Wt        = (ushort*)(ws + meta + sz_y + sz_xb);

  const bool fast_ok = (n <= 65536) && (nbuk <= NBUK_MAX) && (nbuk <= 1024) &&
                       (ntot % 4u == 0u) && (in_sizes[0] == n * 128) &&
                       (in_sizes[4] == 512 * 128) &&
                       (ws_size >= meta + sz_y + sz_xb + sz_wt);

  if (fast_ok) {
    const unsigned chunk = (((ntot + NBLK - 1u) / NBLK) + 7u) & ~7u;
    const int nx8 = n * 16;
    const int nprep = (nx8 + 8192 + 255) / 256;
    hipMemsetAsync(cnt, 0, (size_t)nbuk * 4, stream);
    histprep_kernel<<<dim3(NBLK + nprep), dim3(256), 0, stream>>>(
        rows, cnt, cnt2, X, W, Xb, Wt, ntot, nbuk, chunk, nx8);
    scanB2_kernel<<<dim3((nbuk + 3) / 4), dim3(256), 0, stream>>>(
        cnt, cnt2, pstartX, bstart2, row_start, nbuk, n, ntot);
    bscatter2_kernel<<<dim3(NBLK), dim3(256), 0, stream>>>(
        rows, cols, vals, bstart2, staged, ntot, epb, nbuk, chunk);
    const int nby = (n + 63) / 64;
    reordmm_kernel<<<dim3(nbuk + 8 * nby), dim3(256), 0, stream>>>(
        cnt, pstartX, staged, ep, row_start, Xb, Wt, Y, n, nbuk);
    const unsigned gblk = (unsigned)((n + 3) / 4);
    gather_kernel<<<dim3(gblk), dim3(256), 0, stream>>>(
        row_start, ep, Y, bias, out, n);
    return;
  }

  // Fallback: atomic path (fp32 vector gemm)
  {
    const int nquads = n * 32;
    init_out_kernel<<<dim3((nquads + 255) / 256), dim3(256), 0, stream>>>(out, bias, nquads);
    float* Yf = (float*)d_ws;
    const size_t need_fused = (size_t)n * 512 * sizeof(float);
    if (ws_size >= need_fused) {
      dim3 g(512 / 64, (n + 63) / 64);
      gemm_kernel<float><<<g, dim3(256), 0, stream>>>(X, W, Yf, n, 0, 512);
      const unsigned nblk = (ntot + 7) / 8;
      scatter_kernel<<<dim3(nblk), dim3(256), 0, stream>>>(
          rows, cols, vals, Yf, 512, 128, epb, ntot, out);
    } else {
      for (unsigned b = 0; b < 4; ++b) {
        dim3 g(128 / 64, (n + 63) / 64);
        gemm_kernel<float><<<g, dim3(256), 0, stream>>>(X, W, Yf, n, (int)(b * 128), 128);
        const unsigned nblk = (epb + 7) / 8;
        scatter_kernel<<<dim3(nblk), dim3(256), 0, stream>>>(
            rows + (size_t)b * epb, cols + (size_t)b * epb, vals + (size_t)b * epb,
            Yf, 128, 0, epb, epb, out);
      }
    }
  }
}